// Round 1
// baseline (4094.130 us; speedup 1.0000x reference)
//
#include <hip/hip_runtime.h>
#include <math.h>

#define CH 256
#define GRP 16
#define EPSV 1e-5f
#define BB 4
#define TPIX 16

__device__ __forceinline__ float hsig(float x){
  return fminf(fmaxf((x + 3.0f) * (1.0f/6.0f), 0.0f), 1.0f);
}

// wT[(c*9+k)*256 + o] = w[(o*256+c)*9 + k]
__global__ __launch_bounds__(256) void transpose_w_kernel(const float* __restrict__ w, float* __restrict__ wT){
  int t = blockIdx.x * 256 + threadIdx.x;   // 0..589823
  int o = t & 255;
  int ck = t >> 8;
  int c = ck / 9, k = ck - c * 9;
  wT[t] = w[(o * CH + c) * 9 + k];
}

// conv3x3 Cin=256 -> 27ch; one thread per output pixel, all 27 channels.
__global__ __launch_bounds__(256) void conv_offset_kernel(
    const float* __restrict__ x, const float* __restrict__ woff, const float* __restrict__ boff,
    float* __restrict__ offset, float* __restrict__ mask, int H, int W){
  __shared__ float wl[32 * 243];
  int t = threadIdx.x;
  int pix = blockIdx.x * 256 + t;
  int HW = H * W;
  int b = pix / HW;
  int rem = pix - b * HW;
  int h = rem / W;
  int w = rem - h * W;
  float acc[27];
  #pragma unroll
  for (int o = 0; o < 27; o++) acc[o] = boff[o];
  const float* xb = x + b * CH * HW;
  for (int c0 = 0; c0 < CH; c0 += 32){
    __syncthreads();
    for (int i = t; i < 32 * 243; i += 256){
      int cc = i / 243, r = i - cc * 243;
      int o = r / 9, kk = r - o * 9;
      wl[i] = woff[o * (CH * 9) + (c0 + cc) * 9 + kk];
    }
    __syncthreads();
    for (int cc = 0; cc < 32; cc++){
      const float* xc = xb + (c0 + cc) * HW;
      float xv[9];
      #pragma unroll
      for (int ky = 0; ky < 3; ky++){
        int hh = h + ky - 1;
        #pragma unroll
        for (int kx = 0; kx < 3; kx++){
          int ww = w + kx - 1;
          xv[ky * 3 + kx] = (hh >= 0 && hh < H && ww >= 0 && ww < W) ? xc[hh * W + ww] : 0.0f;
        }
      }
      const float* wc = &wl[cc * 243];
      #pragma unroll
      for (int o = 0; o < 27; o++){
        float a = acc[o];
        #pragma unroll
        for (int kk = 0; kk < 9; kk++) a += xv[kk] * wc[o * 9 + kk];
        acc[o] = a;
      }
    }
  }
  #pragma unroll
  for (int o = 0; o < 18; o++) offset[(b * 18 + o) * HW + rem] = acc[o];
  #pragma unroll
  for (int o = 18; o < 27; o++) mask[(b * 9 + (o - 18)) * HW + rem] = 1.0f / (1.0f + expf(-acc[o]));
}

// Modulated deformable conv 3x3. Block: 16 consecutive pixels (one row segment),
// 256 threads = 256 output channels. Per input channel c: 144 threads gather
// bilinear col values into LDS; all threads FMA against wT (coalesced global).
__global__ __launch_bounds__(256) void mdcn_kernel(
    const float* __restrict__ x, int Hx, int Wx,
    const float* __restrict__ offset, const float* __restrict__ mask,
    int Hoff, int Woff, int offstep, int stride,
    const float* __restrict__ wT, float* __restrict__ y, int Ho, int Wo){
  __shared__ float colbuf[TPIX * 12];   // padded stride 12 for aligned float4 reads
  int t = threadIdx.x;
  int base = blockIdx.x * TPIX;
  int HoWo = Ho * Wo;
  int b = base / HoWo;
  int rr = base - b * HoWo;
  int i = rr / Wo;
  int j0 = rr - i * Wo;
  int HxWx = Hx * Wx;

  int a0 = 0, a1 = 0, a2 = 0, a3 = 0, colidx = 0;
  float w0 = 0, w1 = 0, w2 = 0, w3 = 0;
  if (t < TPIX * 9){
    int p = t / 9, k = t - p * 9;
    colidx = p * 12 + k;
    int j = j0 + p;
    int ky = k / 3, kx = k - ky * 3;
    int HoffW = Hoff * Woff;
    int opos = i * offstep * Woff + j * offstep;
    float offy = offset[(b * 18 + 2 * k) * HoffW + opos];
    float offx = offset[(b * 18 + 2 * k + 1) * HoffW + opos];
    float m = mask[(b * 9 + k) * HoffW + opos];
    float py = (float)(i * stride - 1 + ky) + offy;
    float px = (float)(j * stride - 1 + kx) + offx;
    float y0f = floorf(py), x0f = floorf(px);
    float fy = py - y0f, fx = px - x0f;
    bool vy0 = (y0f >= 0.0f) && (y0f <= (float)(Hx - 1));
    bool vy1 = (y0f + 1.0f >= 0.0f) && (y0f + 1.0f <= (float)(Hx - 1));
    bool vx0 = (x0f >= 0.0f) && (x0f <= (float)(Wx - 1));
    bool vx1 = (x0f + 1.0f >= 0.0f) && (x0f + 1.0f <= (float)(Wx - 1));
    w0 = (1.0f - fy) * (1.0f - fx) * m * ((vy0 && vx0) ? 1.0f : 0.0f);
    w1 = (1.0f - fy) * fx * m * ((vy0 && vx1) ? 1.0f : 0.0f);
    w2 = fy * (1.0f - fx) * m * ((vy1 && vx0) ? 1.0f : 0.0f);
    w3 = fy * fx * m * ((vy1 && vx1) ? 1.0f : 0.0f);
    int iy0 = min(max((int)y0f, 0), Hx - 1);
    int iy1 = min(max((int)y0f + 1, 0), Hx - 1);
    int ix0 = min(max((int)x0f, 0), Wx - 1);
    int ix1 = min(max((int)x0f + 1, 0), Wx - 1);
    a0 = iy0 * Wx + ix0; a1 = iy0 * Wx + ix1; a2 = iy1 * Wx + ix0; a3 = iy1 * Wx + ix1;
  }
  float acc[TPIX];
  #pragma unroll
  for (int p2 = 0; p2 < TPIX; p2++) acc[p2] = 0.0f;
  const float* xb = x + b * CH * HxWx;
  for (int c = 0; c < CH; c++){
    __syncthreads();
    if (t < TPIX * 9){
      const float* xp = xb + c * HxWx;
      colbuf[colidx] = w0 * xp[a0] + w1 * xp[a1] + w2 * xp[a2] + w3 * xp[a3];
    }
    __syncthreads();
    const float* wc = wT + c * (9 * CH) + t;
    float wr[9];
    #pragma unroll
    for (int r = 0; r < 9; r++) wr[r] = wc[r * CH];
    #pragma unroll
    for (int p2 = 0; p2 < TPIX; p2++){
      const float4* cb = (const float4*)(&colbuf[p2 * 12]);
      float4 cA = cb[0];
      float4 cB = cb[1];
      float c8 = colbuf[p2 * 12 + 8];
      acc[p2] += cA.x * wr[0] + cA.y * wr[1] + cA.z * wr[2] + cA.w * wr[3]
               + cB.x * wr[4] + cB.y * wr[5] + cB.z * wr[6] + cB.w * wr[7] + c8 * wr[8];
    }
  }
  float* yb = y + (b * CH + t) * HoWo + i * Wo + j0;
  #pragma unroll
  for (int p2 = 0; p2 < TPIX; p2++) yb[p2] = acc[p2];
}

// per-(b,c) sums: sum, sumsq, optional weighted sum (rowsum[i]*rowsum[j])
__global__ __launch_bounds__(256) void stats_kernel(
    const float* __restrict__ yv, float* __restrict__ sums, float* __restrict__ sumsq,
    float* __restrict__ wsum, const float* __restrict__ roww, int Hs, int Ws){
  int bc = blockIdx.x;
  int t = threadIdx.x;
  const float* p = yv + (long)bc * Hs * Ws;
  float s = 0, ss = 0, ws = 0;
  int N = Hs * Ws;
  for (int idx = t; idx < N; idx += 256){
    float v = p[idx];
    s += v; ss += v * v;
    if (roww){ int r = idx / Ws, cc = idx - r * Ws; ws += v * roww[r] * roww[cc]; }
  }
  __shared__ float r1[256], r2[256], r3[256];
  r1[t] = s; r2[t] = ss; r3[t] = ws;
  __syncthreads();
  for (int o = 128; o > 0; o >>= 1){
    if (t < o){ r1[t] += r1[t + o]; r2[t] += r2[t + o]; r3[t] += r3[t + o]; }
    __syncthreads();
  }
  if (t == 0){ sums[bc] = r1[0]; sumsq[bc] = r2[0]; if (wsum) wsum[bc] = r3[0]; }
}

// total upsample contribution weight of each source row (align-corners, deterministic)
__global__ __launch_bounds__(64) void rowsum_kernel(float* __restrict__ roww, int Hh, int H){
  int i = threadIdx.x;
  if (i < Hh){
    float rs = 0.0f;
    float scale = (float)(Hh - 1) / (float)(H - 1);
    for (int h = 0; h < H; h++){
      float ysv = (float)h * scale;
      float y0f = floorf(ysv);
      int y0 = (int)y0f;
      float fy = ysv - y0f;
      int y1 = min(y0 + 1, Hh - 1);
      if (y0 == i) rs += 1.0f - fy;
      if (y1 == i) rs += fy;
    }
    roww[i] = rs;
  }
}

// group stats (mu, rsqrt) + scale_attn scalar per batch
__global__ __launch_bounds__(256) void gn_sa_kernel(
    const float* __restrict__ sums, const float* __restrict__ sumsq,
    const float* __restrict__ psums, float pdiv_inv, float n_inv,
    const float* __restrict__ gw, const float* __restrict__ gb,
    const float* __restrict__ saw, const float* __restrict__ sab,
    float* __restrict__ mu_o, float* __restrict__ rs_o, float* __restrict__ v_o){
  int b = blockIdx.x; int t = threadIdx.x;
  __shared__ float smu[GRP], srs[GRP], red[256];
  if (t < GRP){
    float s = 0, ss = 0;
    for (int c = 0; c < 16; c++){ int idx = b * CH + t * 16 + c; s += sums[idx]; ss += sumsq[idx]; }
    float mu = s * n_inv;
    float var = ss * n_inv - mu * mu;
    float rs = rsqrtf(var + EPSV);
    smu[t] = mu; srs[t] = rs;
    mu_o[b * GRP + t] = mu; rs_o[b * GRP + t] = rs;
  }
  __syncthreads();
  int g = t >> 4;
  float pm = (psums[b * CH + t] * pdiv_inv - smu[g]) * srs[g] * gw[t] + gb[t];
  red[t] = pm * saw[t];
  __syncthreads();
  for (int o = 128; o > 0; o >>= 1){ if (t < o) red[t] += red[t + o]; __syncthreads(); }
  if (t == 0) v_o[b] = hsig(fmaxf(red[0] + sab[0], 0.0f));
}

// s = (v_mid*GN(mid) + v_lo*GN(lo) + v_hi*GN(upsample(hi))) / cnt    (in-place into y_mid)
__global__ __launch_bounds__(256) void combine_kernel(
    float* __restrict__ smid, const float* __restrict__ ylo, const float* __restrict__ yhi,
    const float* __restrict__ mu_m, const float* __restrict__ rs_m, const float* __restrict__ gw_m, const float* __restrict__ gb_m, const float* __restrict__ v_m,
    const float* __restrict__ mu_l, const float* __restrict__ rs_l, const float* __restrict__ gw_l, const float* __restrict__ gb_l, const float* __restrict__ v_l,
    const float* __restrict__ mu_h, const float* __restrict__ rs_h, const float* __restrict__ gw_h, const float* __restrict__ gb_h, const float* __restrict__ v_h,
    int H, int W, int has_lo, int has_hi, float inv_cnt){
  int idx = blockIdx.x * 256 + threadIdx.x;
  int HW = H * W;
  int b = idx / (CH * HW);
  int r1 = idx - b * CH * HW;
  int c = r1 / HW;
  int rem = r1 - c * HW;
  int h = rem / W;
  int w = rem - h * W;
  int g = c >> 4;
  int bg = b * GRP + g;
  float s = v_m[b] * ((smid[idx] - mu_m[bg]) * rs_m[bg] * gw_m[c] + gb_m[c]);
  if (has_lo) s += v_l[b] * ((ylo[idx] - mu_l[bg]) * rs_l[bg] * gw_l[c] + gb_l[c]);
  if (has_hi){
    int Hh = H >> 1, Wh = W >> 1;
    float ysv = (float)h * ((float)(Hh - 1) / (float)(H - 1));
    float y0f = floorf(ysv); int y0 = (int)y0f; float fy = ysv - y0f; int y1 = min(y0 + 1, Hh - 1);
    float xsv = (float)w * ((float)(Wh - 1) / (float)(W - 1));
    float x0f = floorf(xsv); int x0 = (int)x0f; float fx = xsv - x0f; int x1 = min(x0 + 1, Wh - 1);
    const float* hb = yhi + (b * CH + c) * Hh * Wh;
    float v00 = hb[y0 * Wh + x0], v01 = hb[y0 * Wh + x1];
    float v10 = hb[y1 * Wh + x0], v11 = hb[y1 * Wh + x1];
    float bl = v00 * (1 - fy) * (1 - fx) + v01 * (1 - fy) * fx + v10 * fy * (1 - fx) + v11 * fy * fx;
    s += v_h[b] * ((bl - mu_h[bg]) * rs_h[bg] * gw_h[c] + gb_h[c]);
  }
  smid[idx] = s * inv_cnt;
}

// per-batch dyrelu MLP -> a1, c1, a2, c2 per channel
__global__ __launch_bounds__(256) void dyrelu_coef_kernel(
    const float* __restrict__ psum, float inv_hw,
    const float* __restrict__ w1, const float* __restrict__ b1,
    const float* __restrict__ w2, const float* __restrict__ b2,
    float* __restrict__ coef){
  int b = blockIdx.x; int t = threadIdx.x;
  __shared__ float pl[CH], hl[64];
  pl[t] = psum[b * CH + t] * inv_hw;
  __syncthreads();
  if (t < 64){
    float a = b1[t];
    const float* wr = w1 + t * CH;
    for (int c = 0; c < CH; c++) a += wr[c] * pl[c];
    hl[t] = fmaxf(a, 0.0f);
  }
  __syncthreads();
  #pragma unroll
  for (int r = 0; r < 4; r++){
    int o = r * CH + t;
    float a = b2[o];
    const float* wr = w2 + o * 64;
    #pragma unroll
    for (int j = 0; j < 64; j++) a += wr[j] * hl[j];
    float co = hsig(a) - 0.5f;
    float outv;
    if (r == 0) outv = co * 2.0f + 1.0f;
    else if (r == 2) outv = co * 2.0f;
    else outv = co;
    coef[(b * 4 + r) * CH + t] = outv;
  }
}

__global__ __launch_bounds__(256) void final_kernel(
    const float* __restrict__ s, const float* __restrict__ coef, float* __restrict__ outp, int HW){
  int idx = blockIdx.x * 256 + threadIdx.x;
  int b = idx / (CH * HW);
  int c = (idx - b * CH * HW) / HW;
  const float* cf = coef + b * 4 * CH;
  float a1 = cf[c], c1 = cf[CH + c], a2 = cf[2 * CH + c], c2 = cf[3 * CH + c];
  float xv = s[idx];
  outp[idx] = fmaxf(xv * a1 + c1, xv * a2 + c2);
}

extern "C" void kernel_launch(void* const* d_in, const int* in_sizes, int n_in,
                              void* d_out, int out_size, void* d_ws, size_t ws_size,
                              hipStream_t stream){
  const float* x[3] = {(const float*)d_in[0], (const float*)d_in[1], (const float*)d_in[2]};
  const float* w_off = (const float*)d_in[3];
  const float* b_off = (const float*)d_in[4];
  // Disambiguate input ordering: dict order has w_mid (589824) at slot 6,
  // signature order has gn_high_w (256) there.
  int sig = (in_sizes[6] == 256);
  const float* w_high = (const float*)d_in[5];
  const float* w_mid  = (const float*)d_in[sig ? 8 : 6];
  const float* w_low  = (const float*)d_in[sig ? 11 : 7];
  const float* gn_high_w = (const float*)d_in[sig ? 6 : 8];
  const float* gn_high_b = (const float*)d_in[sig ? 7 : 9];
  const float* gn_mid_w  = (const float*)d_in[sig ? 9 : 10];
  const float* gn_mid_b  = (const float*)d_in[sig ? 10 : 11];
  const float* gn_low_w  = (const float*)d_in[12];
  const float* gn_low_b  = (const float*)d_in[13];
  const float* sa_w  = (const float*)d_in[14];
  const float* sa_b  = (const float*)d_in[15];
  const float* dy_w1 = (const float*)d_in[16];
  const float* dy_b1 = (const float*)d_in[17];
  const float* dy_w2 = (const float*)d_in[18];
  const float* dy_b2 = (const float*)d_in[19];

  float* p = (float*)d_ws;
  float* wT_mid  = p; p += 589824;
  float* wT_low  = p; p += 589824;
  float* wT_high = p; p += 589824;
  float* offs    = p; p += 294912;    // B*18*64*64 max
  float* maskb   = p; p += 147456;    // B*9*64*64 max
  float* y_mid   = p; p += 4194304;   // B*256*64*64 max
  float* y_lo    = p; p += 1048576;
  float* y_hi    = p; p += 1048576;
  float* sum_m = p; p += 1024;  float* ss_m = p; p += 1024;
  float* sum_l = p; p += 1024;  float* ss_l = p; p += 1024;
  float* sum_h = p; p += 1024;  float* ss_h = p; p += 1024;
  float* wsum_h = p; p += 1024;
  float* psum   = p; p += 1024;
  float* mu_m = p; p += 64;  float* rs_m = p; p += 64;
  float* mu_l = p; p += 64;  float* rs_l = p; p += 64;
  float* mu_h = p; p += 64;  float* rs_h = p; p += 64;
  float* v_m = p; p += 16;   float* v_l = p; p += 16;  float* v_h = p; p += 16;
  float* roww = p; p += 64;
  float* coefb = p; p += 4096;

  transpose_w_kernel<<<2304, 256, 0, stream>>>(w_mid,  wT_mid);
  transpose_w_kernel<<<2304, 256, 0, stream>>>(w_low,  wT_low);
  transpose_w_kernel<<<2304, 256, 0, stream>>>(w_high, wT_high);

  long out_off = 0;
  for (int lvl = 0; lvl < 3; lvl++){
    int H = 64 >> lvl, W = H;
    int HW = H * W;
    int has_lo = (lvl > 0) ? 1 : 0;
    int has_hi = (lvl < 2) ? 1 : 0;

    conv_offset_kernel<<<BB * HW / 256, 256, 0, stream>>>(x[lvl], w_off, b_off, offs, maskb, H, W);

    mdcn_kernel<<<BB * HW / TPIX, 256, 0, stream>>>(x[lvl], H, W, offs, maskb, H, W, 1, 1, wT_mid, y_mid, H, W);
    if (has_lo)
      mdcn_kernel<<<BB * HW / TPIX, 256, 0, stream>>>(x[lvl - 1], 2 * H, 2 * W, offs, maskb, H, W, 1, 2, wT_low, y_lo, H, W);
    if (has_hi)
      mdcn_kernel<<<BB * (HW / 4) / TPIX, 256, 0, stream>>>(x[lvl + 1], H / 2, W / 2, offs, maskb, H, W, 2, 1, wT_high, y_hi, H / 2, W / 2);

    stats_kernel<<<BB * CH, 256, 0, stream>>>(y_mid, sum_m, ss_m, nullptr, nullptr, H, W);
    if (has_lo) stats_kernel<<<BB * CH, 256, 0, stream>>>(y_lo, sum_l, ss_l, nullptr, nullptr, H, W);
    if (has_hi){
      rowsum_kernel<<<1, 64, 0, stream>>>(roww, H / 2, H);
      stats_kernel<<<BB * CH, 256, 0, stream>>>(y_hi, sum_h, ss_h, wsum_h, roww, H / 2, W / 2);
    }

    float invHW = 1.0f / (float)HW;
    gn_sa_kernel<<<BB, 256, 0, stream>>>(sum_m, ss_m, sum_m, invHW, 1.0f / (16.0f * HW),
                                         gn_mid_w, gn_mid_b, sa_w, sa_b, mu_m, rs_m, v_m);
    if (has_lo)
      gn_sa_kernel<<<BB, 256, 0, stream>>>(sum_l, ss_l, sum_l, invHW, 1.0f / (16.0f * HW),
                                           gn_low_w, gn_low_b, sa_w, sa_b, mu_l, rs_l, v_l);
    if (has_hi)
      gn_sa_kernel<<<BB, 256, 0, stream>>>(sum_h, ss_h, wsum_h, invHW, 1.0f / (16.0f * (HW / 4)),
                                           gn_high_w, gn_high_b, sa_w, sa_b, mu_h, rs_h, v_h);

    float cnt = 1.0f + (float)has_lo + (float)has_hi;
    combine_kernel<<<BB * CH * HW / 256, 256, 0, stream>>>(
        y_mid, y_lo, y_hi,
        mu_m, rs_m, gn_mid_w, gn_mid_b, v_m,
        mu_l, rs_l, gn_low_w, gn_low_b, v_l,
        mu_h, rs_h, gn_high_w, gn_high_b, v_h,
        H, W, has_lo, has_hi, 1.0f / cnt);

    stats_kernel<<<BB * CH, 256, 0, stream>>>(y_mid, psum, ss_m, nullptr, nullptr, H, W);
    dyrelu_coef_kernel<<<BB, 256, 0, stream>>>(psum, invHW, dy_w1, dy_b1, dy_w2, dy_b2, coefb);
    final_kernel<<<BB * CH * HW / 256, 256, 0, stream>>>(y_mid, coefb, (float*)d_out + out_off, HW);
    out_off += (long)BB * CH * HW;
  }
}

// Round 2
// 3081.065 us; speedup vs baseline: 1.3288x; 1.3288x over previous
//
#include <hip/hip_runtime.h>
#include <math.h>

#define CH 256
#define GRP 16
#define EPSV 1e-5f
#define BB 4

typedef __attribute__((ext_vector_type(8))) short short8;
typedef __attribute__((ext_vector_type(4))) float f32x4;

__device__ __forceinline__ float hsig(float x){
  return fminf(fmaxf((x + 3.0f) * (1.0f/6.0f), 0.0f), 1.0f);
}

__device__ __forceinline__ unsigned short f2bf(float f){
  union { float f; unsigned int u; } v; v.f = f;
  unsigned int r = v.u + 0x7fffu + ((v.u >> 16) & 1u);
  return (unsigned short)(r >> 16);
}

__device__ __forceinline__ void gload_lds16(const void* g, void* l){
  __builtin_amdgcn_global_load_lds((const __attribute__((address_space(1))) unsigned int*)g,
                                   (__attribute__((address_space(3))) unsigned int*)l, 16, 0, 0);
}

// Pack conv weight w[o][c][kk] (fp32) into 72 K-step tiles of bf16, pre-swizzled:
// tile s = kk*8 + cb holds A[o=0..255][kc=0..31] (c = cb*32+kc), element offset
// o*32 + ((kc>>3) ^ ((o>>1)&3))*8 + (kc&7)   (XOR on the 16B chunk index).
__global__ __launch_bounds__(256) void pack_w_kernel(const float* __restrict__ w, unsigned short* __restrict__ W3){
  int idx = blockIdx.x * 256 + threadIdx.x;   // 0..589823
  int s = idx >> 13;
  int r = idx & 8191;
  int o = r >> 5;
  int pos = r & 31;
  int cp = pos >> 3, j = pos & 7;
  int kc = ((cp ^ ((o >> 1) & 3)) << 3) + j;
  int kk = s >> 3, cb = s & 7;
  int c = (cb << 5) + kc;
  W3[idx] = f2bf(w[((o << 8) + c) * 9 + kk]);
}

// conv3x3 Cin=256 -> 27ch; one thread per output pixel, all 27 channels.
__global__ __launch_bounds__(256) void conv_offset_kernel(
    const float* __restrict__ x, const float* __restrict__ woff, const float* __restrict__ boff,
    float* __restrict__ offset, float* __restrict__ mask, int H, int W){
  __shared__ float wl[32 * 243];
  int t = threadIdx.x;
  int pix = blockIdx.x * 256 + t;
  int HW = H * W;
  int b = pix / HW;
  int rem = pix - b * HW;
  int h = rem / W;
  int w = rem - h * W;
  float acc[27];
  #pragma unroll
  for (int o = 0; o < 27; o++) acc[o] = boff[o];
  const float* xb = x + b * CH * HW;
  for (int c0 = 0; c0 < CH; c0 += 32){
    __syncthreads();
    for (int i = t; i < 32 * 243; i += 256){
      int cc = i / 243, r = i - cc * 243;
      int o = r / 9, kk = r - o * 9;
      wl[i] = woff[o * (CH * 9) + (c0 + cc) * 9 + kk];
    }
    __syncthreads();
    for (int cc = 0; cc < 32; cc++){
      const float* xc = xb + (c0 + cc) * HW;
      float xv[9];
      #pragma unroll
      for (int ky = 0; ky < 3; ky++){
        int hh = h + ky - 1;
        #pragma unroll
        for (int kx = 0; kx < 3; kx++){
          int ww = w + kx - 1;
          xv[ky * 3 + kx] = (hh >= 0 && hh < H && ww >= 0 && ww < W) ? xc[hh * W + ww] : 0.0f;
        }
      }
      const float* wc = &wl[cc * 243];
      #pragma unroll
      for (int o = 0; o < 27; o++){
        float a = acc[o];
        #pragma unroll
        for (int kk = 0; kk < 9; kk++) a += xv[kk] * wc[o * 9 + kk];
        acc[o] = a;
      }
    }
  }
  #pragma unroll
  for (int o = 0; o < 18; o++) offset[(b * 18 + o) * HW + rem] = acc[o];
  #pragma unroll
  for (int o = 18; o < 27; o++) mask[(b * 9 + (o - 18)) * HW + rem] = 1.0f / (1.0f + expf(-acc[o]));
}

// Modulated deformable conv as fused im2col + bf16 MFMA GEMM.
// Block: 64 output pixels x all 256 output channels; 4 waves, wave w owns
// output channels [w*64, w*64+64). K = 2304 ordered kk-major, c-minor.
__global__ __launch_bounds__(256, 4) void mdcn_mfma_kernel(
    const float* __restrict__ x, int Hx, int Wx,
    const float* __restrict__ offs, const float* __restrict__ maskb,
    int Hoff, int Woff, int offstep, int stride,
    const unsigned short* __restrict__ W3, float* __restrict__ y, int Ho, int Wo){
  __shared__ __align__(16) short wlds[8192];     // 16 KB: A tile [256 o][32 kc] swizzled
  __shared__ __align__(16) short colbuf[2048];   // 4 KB:  B tile [64 n][32 kc] swizzled
  __shared__ int4  sAddr[9][64];
  __shared__ float4 sWgt[9][64];

  int t = threadIdx.x;
  int lane = t & 63;
  int wv = t >> 6;
  int HoWo = Ho * Wo;
  int blkPerB = HoWo >> 6;
  int b = blockIdx.x / blkPerB;
  int n0 = (blockIdx.x - b * blkPerB) << 6;
  int HxWx = Hx * Wx;
  int HoffW = Hoff * Woff;

  // ---- precompute bilinear corners + weights (incl. mask) per (kk, n) ----
  for (int idx = t; idx < 576; idx += 256){
    int kk = idx >> 6, n = idx & 63;
    int pix = n0 + n;
    int i = pix / Wo, j = pix - i * Wo;
    int ky = kk / 3, kx = kk - ky * 3;
    int opos = i * offstep * Woff + j * offstep;
    float offy = offs[((long)b * 18 + 2 * kk) * HoffW + opos];
    float offx = offs[((long)b * 18 + 2 * kk + 1) * HoffW + opos];
    float m = maskb[((long)b * 9 + kk) * HoffW + opos];
    float py = (float)(i * stride - 1 + ky) + offy;
    float px = (float)(j * stride - 1 + kx) + offx;
    float y0f = floorf(py), x0f = floorf(px);
    float fy = py - y0f, fx = px - x0f;
    bool vy0 = (y0f >= 0.0f) && (y0f <= (float)(Hx - 1));
    bool vy1 = (y0f + 1.0f >= 0.0f) && (y0f + 1.0f <= (float)(Hx - 1));
    bool vx0 = (x0f >= 0.0f) && (x0f <= (float)(Wx - 1));
    bool vx1 = (x0f + 1.0f >= 0.0f) && (x0f + 1.0f <= (float)(Wx - 1));
    float w0 = (1.0f - fy) * (1.0f - fx) * m * ((vy0 && vx0) ? 1.0f : 0.0f);
    float w1 = (1.0f - fy) * fx * m * ((vy0 && vx1) ? 1.0f : 0.0f);
    float w2 = fy * (1.0f - fx) * m * ((vy1 && vx0) ? 1.0f : 0.0f);
    float w3 = fy * fx * m * ((vy1 && vx1) ? 1.0f : 0.0f);
    int iy0 = min(max((int)y0f, 0), Hx - 1);
    int iy1 = min(max((int)y0f + 1, 0), Hx - 1);
    int ix0 = min(max((int)x0f, 0), Wx - 1);
    int ix1 = min(max((int)x0f + 1, 0), Wx - 1);
    sAddr[kk][n] = make_int4(iy0 * Wx + ix0, iy0 * Wx + ix1, iy1 * Wx + ix0, iy1 * Wx + ix1);
    sWgt[kk][n] = make_float4(w0, w1, w2, w3);
  }
  __syncthreads();

  f32x4 acc[4][4];
  #pragma unroll
  for (int mf = 0; mf < 4; mf++)
    #pragma unroll
    for (int nf = 0; nf < 4; nf++)
      acc[mf][nf] = (f32x4){0.f, 0.f, 0.f, 0.f};

  const char* wb = (const char*)wlds;
  const char* cbuf = (const char*)colbuf;

  for (int kk = 0; kk < 9; kk++){
    int4 A4 = sAddr[kk][lane];
    float4 Wt = sWgt[kk][lane];
    for (int cb = 0; cb < 8; cb++){
      __syncthreads();   // previous step's MFMA reads done
      // stage A tile (pre-swizzled in global -> linear LDS)
      const unsigned short* tile = W3 + (size_t)(kk * 8 + cb) * 8192;
      #pragma unroll
      for (int i = 0; i < 4; i++){
        int q = wv * 4 + i;
        gload_lds16(tile + q * 512 + lane * 8, (void*)(wlds + q * 512));
      }
      // compute B tile: this thread -> pixel `lane`, channels cb*32 + wv*8 .. +8
      const float* xb0 = x + ((long)b * CH + cb * 32 + wv * 8) * HxWx;
      short8 pk;
      #pragma unroll
      for (int j = 0; j < 8; j++){
        const float* xp = xb0 + j * HxWx;
        float v = Wt.x * xp[A4.x] + Wt.y * xp[A4.y] + Wt.z * xp[A4.z] + Wt.w * xp[A4.w];
        pk[j] = (short)f2bf(v);
      }
      *(short8*)((char*)colbuf + lane * 64 + ((wv ^ ((lane >> 1) & 3)) << 4)) = pk;
      __syncthreads();   // drains vmcnt (global_load_lds) + lgkm
      // MFMA phase
      short8 af[4];
      #pragma unroll
      for (int mf = 0; mf < 4; mf++){
        int o = wv * 64 + mf * 16 + (lane & 15);
        af[mf] = *(const short8*)(wb + o * 64 + ((((lane >> 4)) ^ ((o >> 1) & 3)) << 4));
      }
      short8 bfr[4];
      #pragma unroll
      for (int nf = 0; nf < 4; nf++){
        int nc = nf * 16 + (lane & 15);
        bfr[nf] = *(const short8*)(cbuf + nc * 64 + ((((lane >> 4)) ^ ((nc >> 1) & 3)) << 4));
      }
      #pragma unroll
      for (int mf = 0; mf < 4; mf++)
        #pragma unroll
        for (int nf = 0; nf < 4; nf++)
          acc[mf][nf] = __builtin_amdgcn_mfma_f32_16x16x32_bf16(af[mf], bfr[nf], acc[mf][nf], 0, 0, 0);
    }
  }

  // write C: row = o (M), col = pixel (N)
  #pragma unroll
  for (int mf = 0; mf < 4; mf++){
    #pragma unroll
    for (int nf = 0; nf < 4; nf++){
      #pragma unroll
      for (int r = 0; r < 4; r++){
        int o = wv * 64 + mf * 16 + (lane >> 4) * 4 + r;
        int pix = n0 + nf * 16 + (lane & 15);
        y[((long)b * CH + o) * HoWo + pix] = acc[mf][nf][r];
      }
    }
  }
}

// per-(b,c) sums: sum, sumsq, optional weighted sum (rowsum[i]*rowsum[j])
__global__ __launch_bounds__(256) void stats_kernel(
    const float* __restrict__ yv, float* __restrict__ sums, float* __restrict__ sumsq,
    float* __restrict__ wsum, const float* __restrict__ roww, int Hs, int Ws){
  int bc = blockIdx.x;
  int t = threadIdx.x;
  const float* p = yv + (long)bc * Hs * Ws;
  float s = 0, ss = 0, ws = 0;
  int N = Hs * Ws;
  for (int idx = t; idx < N; idx += 256){
    float v = p[idx];
    s += v; ss += v * v;
    if (roww){ int r = idx / Ws, cc = idx - r * Ws; ws += v * roww[r] * roww[cc]; }
  }
  __shared__ float r1[256], r2[256], r3[256];
  r1[t] = s; r2[t] = ss; r3[t] = ws;
  __syncthreads();
  for (int o = 128; o > 0; o >>= 1){
    if (t < o){ r1[t] += r1[t + o]; r2[t] += r2[t + o]; r3[t] += r3[t + o]; }
    __syncthreads();
  }
  if (t == 0){ sums[bc] = r1[0]; sumsq[bc] = r2[0]; if (wsum) wsum[bc] = r3[0]; }
}

__global__ __launch_bounds__(64) void rowsum_kernel(float* __restrict__ roww, int Hh, int H){
  int i = threadIdx.x;
  if (i < Hh){
    float rs = 0.0f;
    float scale = (float)(Hh - 1) / (float)(H - 1);
    for (int h = 0; h < H; h++){
      float ysv = (float)h * scale;
      float y0f = floorf(ysv);
      int y0 = (int)y0f;
      float fy = ysv - y0f;
      int y1 = min(y0 + 1, Hh - 1);
      if (y0 == i) rs += 1.0f - fy;
      if (y1 == i) rs += fy;
    }
    roww[i] = rs;
  }
}

__global__ __launch_bounds__(256) void gn_sa_kernel(
    const float* __restrict__ sums, const float* __restrict__ sumsq,
    const float* __restrict__ psums, float pdiv_inv, float n_inv,
    const float* __restrict__ gw, const float* __restrict__ gb,
    const float* __restrict__ saw, const float* __restrict__ sab,
    float* __restrict__ mu_o, float* __restrict__ rs_o, float* __restrict__ v_o){
  int b = blockIdx.x; int t = threadIdx.x;
  __shared__ float smu[GRP], srs[GRP], red[256];
  if (t < GRP){
    float s = 0, ss = 0;
    for (int c = 0; c < 16; c++){ int idx = b * CH + t * 16 + c; s += sums[idx]; ss += sumsq[idx]; }
    float mu = s * n_inv;
    float var = ss * n_inv - mu * mu;
    float rs = rsqrtf(var + EPSV);
    smu[t] = mu; srs[t] = rs;
    mu_o[b * GRP + t] = mu; rs_o[b * GRP + t] = rs;
  }
  __syncthreads();
  int g = t >> 4;
  float pm = (psums[b * CH + t] * pdiv_inv - smu[g]) * srs[g] * gw[t] + gb[t];
  red[t] = pm * saw[t];
  __syncthreads();
  for (int o = 128; o > 0; o >>= 1){ if (t < o) red[t] += red[t + o]; __syncthreads(); }
  if (t == 0) v_o[b] = hsig(fmaxf(red[0] + sab[0], 0.0f));
}

__global__ __launch_bounds__(256) void combine_kernel(
    float* __restrict__ smid, const float* __restrict__ ylo, const float* __restrict__ yhi,
    const float* __restrict__ mu_m, const float* __restrict__ rs_m, const float* __restrict__ gw_m, const float* __restrict__ gb_m, const float* __restrict__ v_m,
    const float* __restrict__ mu_l, const float* __restrict__ rs_l, const float* __restrict__ gw_l, const float* __restrict__ gb_l, const float* __restrict__ v_l,
    const float* __restrict__ mu_h, const float* __restrict__ rs_h, const float* __restrict__ gw_h, const float* __restrict__ gb_h, const float* __restrict__ v_h,
    int H, int W, int has_lo, int has_hi, float inv_cnt){
  int idx = blockIdx.x * 256 + threadIdx.x;
  int HW = H * W;
  int b = idx / (CH * HW);
  int r1 = idx - b * CH * HW;
  int c = r1 / HW;
  int rem = r1 - c * HW;
  int h = rem / W;
  int w = rem - h * W;
  int g = c >> 4;
  int bg = b * GRP + g;
  float s = v_m[b] * ((smid[idx] - mu_m[bg]) * rs_m[bg] * gw_m[c] + gb_m[c]);
  if (has_lo) s += v_l[b] * ((ylo[idx] - mu_l[bg]) * rs_l[bg] * gw_l[c] + gb_l[c]);
  if (has_hi){
    int Hh = H >> 1, Wh = W >> 1;
    float ysv = (float)h * ((float)(Hh - 1) / (float)(H - 1));
    float y0f = floorf(ysv); int y0 = (int)y0f; float fy = ysv - y0f; int y1 = min(y0 + 1, Hh - 1);
    float xsv = (float)w * ((float)(Wh - 1) / (float)(W - 1));
    float x0f = floorf(xsv); int x0 = (int)x0f; float fx = xsv - x0f; int x1 = min(x0 + 1, Wh - 1);
    const float* hb = yhi + (b * CH + c) * Hh * Wh;
    float v00 = hb[y0 * Wh + x0], v01 = hb[y0 * Wh + x1];
    float v10 = hb[y1 * Wh + x0], v11 = hb[y1 * Wh + x1];
    float bl = v00 * (1 - fy) * (1 - fx) + v01 * (1 - fy) * fx + v10 * fy * (1 - fx) + v11 * fy * fx;
    s += v_h[b] * ((bl - mu_h[bg]) * rs_h[bg] * gw_h[c] + gb_h[c]);
  }
  smid[idx] = s * inv_cnt;
}

__global__ __launch_bounds__(256) void dyrelu_coef_kernel(
    const float* __restrict__ psum, float inv_hw,
    const float* __restrict__ w1, const float* __restrict__ b1,
    const float* __restrict__ w2, const float* __restrict__ b2,
    float* __restrict__ coef){
  int b = blockIdx.x; int t = threadIdx.x;
  __shared__ float pl[CH], hl[64];
  pl[t] = psum[b * CH + t] * inv_hw;
  __syncthreads();
  if (t < 64){
    float a = b1[t];
    const float* wr = w1 + t * CH;
    for (int c = 0; c < CH; c++) a += wr[c] * pl[c];
    hl[t] = fmaxf(a, 0.0f);
  }
  __syncthreads();
  #pragma unroll
  for (int r = 0; r < 4; r++){
    int o = r * CH + t;
    float a = b2[o];
    const float* wr = w2 + o * 64;
    #pragma unroll
    for (int j = 0; j < 64; j++) a += wr[j] * hl[j];
    float co = hsig(a) - 0.5f;
    float outv;
    if (r == 0) outv = co * 2.0f + 1.0f;
    else if (r == 2) outv = co * 2.0f;
    else outv = co;
    coef[(b * 4 + r) * CH + t] = outv;
  }
}

__global__ __launch_bounds__(256) void final_kernel(
    const float* __restrict__ s, const float* __restrict__ coef, float* __restrict__ outp, int HW){
  int idx = blockIdx.x * 256 + threadIdx.x;
  int b = idx / (CH * HW);
  int c = (idx - b * CH * HW) / HW;
  const float* cf = coef + b * 4 * CH;
  float a1 = cf[c], c1 = cf[CH + c], a2 = cf[2 * CH + c], c2 = cf[3 * CH + c];
  float xv = s[idx];
  outp[idx] = fmaxf(xv * a1 + c1, xv * a2 + c2);
}

extern "C" void kernel_launch(void* const* d_in, const int* in_sizes, int n_in,
                              void* d_out, int out_size, void* d_ws, size_t ws_size,
                              hipStream_t stream){
  const float* x[3] = {(const float*)d_in[0], (const float*)d_in[1], (const float*)d_in[2]};
  const float* w_off = (const float*)d_in[3];
  const float* b_off = (const float*)d_in[4];
  int sig = (in_sizes[6] == 256);
  const float* w_high = (const float*)d_in[5];
  const float* w_mid  = (const float*)d_in[sig ? 8 : 6];
  const float* w_low  = (const float*)d_in[sig ? 11 : 7];
  const float* gn_high_w = (const float*)d_in[sig ? 6 : 8];
  const float* gn_high_b = (const float*)d_in[sig ? 7 : 9];
  const float* gn_mid_w  = (const float*)d_in[sig ? 9 : 10];
  const float* gn_mid_b  = (const float*)d_in[sig ? 10 : 11];
  const float* gn_low_w  = (const float*)d_in[12];
  const float* gn_low_b  = (const float*)d_in[13];
  const float* sa_w  = (const float*)d_in[14];
  const float* sa_b  = (const float*)d_in[15];
  const float* dy_w1 = (const float*)d_in[16];
  const float* dy_b1 = (const float*)d_in[17];
  const float* dy_w2 = (const float*)d_in[18];
  const float* dy_b2 = (const float*)d_in[19];

  float* p = (float*)d_ws;
  unsigned short* W3_mid  = (unsigned short*)p; p += 589824;
  unsigned short* W3_low  = (unsigned short*)p; p += 589824;
  unsigned short* W3_high = (unsigned short*)p; p += 589824;
  float* offs    = p; p += 294912;
  float* maskb   = p; p += 147456;
  float* y_mid   = p; p += 4194304;
  float* y_lo    = p; p += 1048576;
  float* y_hi    = p; p += 1048576;
  float* sum_m = p; p += 1024;  float* ss_m = p; p += 1024;
  float* sum_l = p; p += 1024;  float* ss_l = p; p += 1024;
  float* sum_h = p; p += 1024;  float* ss_h = p; p += 1024;
  float* wsum_h = p; p += 1024;
  float* psum   = p; p += 1024;
  float* mu_m = p; p += 64;  float* rs_m = p; p += 64;
  float* mu_l = p; p += 64;  float* rs_l = p; p += 64;
  float* mu_h = p; p += 64;  float* rs_h = p; p += 64;
  float* v_m = p; p += 16;   float* v_l = p; p += 16;  float* v_h = p; p += 16;
  float* roww = p; p += 64;
  float* coefb = p; p += 4096;

  pack_w_kernel<<<2304, 256, 0, stream>>>(w_mid,  W3_mid);
  pack_w_kernel<<<2304, 256, 0, stream>>>(w_low,  W3_low);
  pack_w_kernel<<<2304, 256, 0, stream>>>(w_high, W3_high);

  long out_off = 0;
  for (int lvl = 0; lvl < 3; lvl++){
    int H = 64 >> lvl, W = H;
    int HW = H * W;
    int has_lo = (lvl > 0) ? 1 : 0;
    int has_hi = (lvl < 2) ? 1 : 0;

    conv_offset_kernel<<<BB * HW / 256, 256, 0, stream>>>(x[lvl], w_off, b_off, offs, maskb, H, W);

    mdcn_mfma_kernel<<<BB * HW / 64, 256, 0, stream>>>(x[lvl], H, W, offs, maskb, H, W, 1, 1, W3_mid, y_mid, H, W);
    if (has_lo)
      mdcn_mfma_kernel<<<BB * HW / 64, 256, 0, stream>>>(x[lvl - 1], 2 * H, 2 * W, offs, maskb, H, W, 1, 2, W3_low, y_lo, H, W);
    if (has_hi)
      mdcn_mfma_kernel<<<BB * (HW / 4) / 64, 256, 0, stream>>>(x[lvl + 1], H / 2, W / 2, offs, maskb, H, W, 2, 1, W3_high, y_hi, H / 2, W / 2);

    stats_kernel<<<BB * CH, 256, 0, stream>>>(y_mid, sum_m, ss_m, nullptr, nullptr, H, W);
    if (has_lo) stats_kernel<<<BB * CH, 256, 0, stream>>>(y_lo, sum_l, ss_l, nullptr, nullptr, H, W);
    if (has_hi){
      rowsum_kernel<<<1, 64, 0, stream>>>(roww, H / 2, H);
      stats_kernel<<<BB * CH, 256, 0, stream>>>(y_hi, sum_h, ss_h, wsum_h, roww, H / 2, W / 2);
    }

    float invHW = 1.0f / (float)HW;
    gn_sa_kernel<<<BB, 256, 0, stream>>>(sum_m, ss_m, sum_m, invHW, 1.0f / (16.0f * HW),
                                         gn_mid_w, gn_mid_b, sa_w, sa_b, mu_m, rs_m, v_m);
    if (has_lo)
      gn_sa_kernel<<<BB, 256, 0, stream>>>(sum_l, ss_l, sum_l, invHW, 1.0f / (16.0f * HW),
                                           gn_low_w, gn_low_b, sa_w, sa_b, mu_l, rs_l, v_l);
    if (has_hi)
      gn_sa_kernel<<<BB, 256, 0, stream>>>(sum_h, ss_h, wsum_h, invHW, 1.0f / (16.0f * (HW / 4)),
                                           gn_high_w, gn_high_b, sa_w, sa_b, mu_h, rs_h, v_h);

    float cnt = 1.0f + (float)has_lo + (float)has_hi;
    combine_kernel<<<BB * CH * HW / 256, 256, 0, stream>>>(
        y_mid, y_lo, y_hi,
        mu_m, rs_m, gn_mid_w, gn_mid_b, v_m,
        mu_l, rs_l, gn_low_w, gn_low_b, v_l,
        mu_h, rs_h, gn_high_w, gn_high_b, v_h,
        H, W, has_lo, has_hi, 1.0f / cnt);

    stats_kernel<<<BB * CH, 256, 0, stream>>>(y_mid, psum, ss_m, nullptr, nullptr, H, W);
    dyrelu_coef_kernel<<<BB, 256, 0, stream>>>(psum, invHW, dy_w1, dy_b1, dy_w2, dy_b2, coefb);
    final_kernel<<<BB * CH * HW / 256, 256, 0, stream>>>(y_mid, coefb, (float*)d_out + out_off, HW);
    out_off += (long)BB * CH * HW;
  }
}

// Round 3
// 2025.638 us; speedup vs baseline: 2.0212x; 1.5210x over previous
//
#include <hip/hip_runtime.h>
#include <math.h>

#define CH 256
#define GRP 16
#define EPSV 1e-5f
#define BB 4

typedef __attribute__((ext_vector_type(8))) short short8;
typedef __attribute__((ext_vector_type(4))) float f32x4;

__device__ __forceinline__ float hsig(float x){
  return fminf(fmaxf((x + 3.0f) * (1.0f/6.0f), 0.0f), 1.0f);
}

__device__ __forceinline__ unsigned short f2bf(float f){
  union { float f; unsigned int u; } v; v.f = f;
  unsigned int r = v.u + 0x7fffu + ((v.u >> 16) & 1u);
  return (unsigned short)(r >> 16);
}

__device__ __forceinline__ void gload_lds16(const void* g, void* l){
  __builtin_amdgcn_global_load_lds((const __attribute__((address_space(1))) unsigned int*)g,
                                   (__attribute__((address_space(3))) unsigned int*)l, 16, 0, 0);
}

// Pack conv weight w[o][c][kk] (fp32, o<256) into 72 K-step tiles of bf16, pre-swizzled:
// tile s = kk*8 + cb holds A[o=0..255][kc=0..31] (c = cb*32+kc), element offset
// o*32 + ((kc>>3) ^ ((o>>1)&3))*8 + (kc&7)   (XOR on the 16B chunk index).
__global__ __launch_bounds__(256) void pack_w_kernel(const float* __restrict__ w, unsigned short* __restrict__ W3){
  int idx = blockIdx.x * 256 + threadIdx.x;   // 0..589823
  int s = idx >> 13;
  int r = idx & 8191;
  int o = r >> 5;
  int pos = r & 31;
  int cp = pos >> 3, j = pos & 7;
  int kc = ((cp ^ ((o >> 1) & 3)) << 3) + j;
  int kk = s >> 3, cb = s & 7;
  int c = (cb << 5) + kc;
  W3[idx] = f2bf(w[((o << 8) + c) * 9 + kk]);
}

// Same packing for the 27-row offset conv weight, padded to 32 rows.
__global__ __launch_bounds__(256) void pack_woff_kernel(const float* __restrict__ w, unsigned short* __restrict__ W27){
  int idx = blockIdx.x * 256 + threadIdx.x;   // 0..73727 (72 tiles x 32 x 32)
  int s = idx >> 10;
  int r = idx & 1023;
  int o = r >> 5;
  int pos = r & 31;
  int cp = pos >> 3, j = pos & 7;
  int kc = ((cp ^ ((o >> 1) & 3)) << 3) + j;
  int kk = s >> 3, cb = s & 7;
  int c = (cb << 5) + kc;
  W27[idx] = (o < 27) ? f2bf(w[(o * CH + c) * 9 + kk]) : (unsigned short)0;
}

// Offset conv3x3 (Cin=256 -> 27ch) as im2col + MFMA GEMM, M=32 (27 padded).
// Block: 256 pixels; 4 waves, wave wv owns pixels [n0+wv*64, +64). K=2304.
__global__ __launch_bounds__(256, 4) void conv_offset_mfma_kernel(
    const float* __restrict__ x, const unsigned short* __restrict__ W27, const float* __restrict__ boff,
    float* __restrict__ offset, float* __restrict__ mask, int H, int W){
  __shared__ __align__(16) short awlds[1024];   // 2 KB  A tile [32 o][32 kc] swizzled
  __shared__ __align__(16) short cbuf[8192];    // 16 KB B tiles: 4 waves x [64 px][32 kc] swizzled
  int t = threadIdx.x;
  int lane = t & 63, wv = t >> 6;
  int HW = H * W;
  int blkPerB = HW >> 8;
  int b = blockIdx.x / blkPerB;
  int n0 = (blockIdx.x - b * blkPerB) << 8;
  int px = n0 + wv * 64 + lane;
  int i = px / W, j = px - i * W;

  const float* xb = x + (long)b * CH * HW;
  char* mycb = (char*)cbuf + wv * 4096;

  f32x4 acc[2][4];
  #pragma unroll
  for (int mf = 0; mf < 2; mf++){
    #pragma unroll
    for (int r = 0; r < 4; r++){
      int o = mf * 16 + (lane >> 4) * 4 + r;
      float bv = boff[o < 27 ? o : 0];
      #pragma unroll
      for (int nf = 0; nf < 4; nf++) acc[mf][nf][r] = bv;
    }
  }

  for (int kk = 0; kk < 9; kk++){
    int ky = kk / 3, kx = kk - ky * 3;
    int ii = i - 1 + ky, jj = j - 1 + kx;
    bool valid = (ii >= 0 && ii < H && jj >= 0 && jj < W);
    int addr = valid ? (ii * W + jj) : 0;
    float vm = valid ? 1.0f : 0.0f;
    for (int cb8 = 0; cb8 < 8; cb8++){
      __syncthreads();   // previous step's MFMA reads done
      const unsigned short* tile = W27 + (size_t)(kk * 8 + cb8) * 1024;
      if (wv < 2) gload_lds16(tile + wv * 512 + lane * 8, (short*)awlds + wv * 512);
      const float* xc = xb + (size_t)(cb8 * 32) * HW + addr;
      #pragma unroll
      for (int q8 = 0; q8 < 4; q8++){
        short8 pk;
        #pragma unroll
        for (int u = 0; u < 8; u++){
          float v = vm * xc[(size_t)(q8 * 8 + u) * HW];
          pk[u] = (short)f2bf(v);
        }
        *(short8*)(mycb + lane * 64 + ((q8 ^ ((lane >> 1) & 3)) << 4)) = pk;
      }
      __syncthreads();   // drains gload_lds + ds_writes
      short8 af[2];
      #pragma unroll
      for (int mf = 0; mf < 2; mf++){
        int o = mf * 16 + (lane & 15);
        af[mf] = *(const short8*)((const char*)awlds + o * 64 + ((((lane >> 4)) ^ ((o >> 1) & 3)) << 4));
      }
      short8 bfr[4];
      #pragma unroll
      for (int nf = 0; nf < 4; nf++){
        int nc = nf * 16 + (lane & 15);
        bfr[nf] = *(const short8*)(mycb + nc * 64 + ((((lane >> 4)) ^ ((nc >> 1) & 3)) << 4));
      }
      #pragma unroll
      for (int mf = 0; mf < 2; mf++)
        #pragma unroll
        for (int nf = 0; nf < 4; nf++)
          acc[mf][nf] = __builtin_amdgcn_mfma_f32_16x16x32_bf16(af[mf], bfr[nf], acc[mf][nf], 0, 0, 0);
    }
  }

  #pragma unroll
  for (int mf = 0; mf < 2; mf++){
    #pragma unroll
    for (int nf = 0; nf < 4; nf++){
      #pragma unroll
      for (int r = 0; r < 4; r++){
        int o = mf * 16 + (lane >> 4) * 4 + r;
        int pix = n0 + wv * 64 + nf * 16 + (lane & 15);
        float v = acc[mf][nf][r];
        if (o < 18) offset[((long)b * 18 + o) * HW + pix] = v;
        else if (o < 27) mask[((long)b * 9 + (o - 18)) * HW + pix] = 1.0f / (1.0f + expf(-v));
      }
    }
  }
}

// Modulated deformable conv as fused im2col + bf16 MFMA GEMM.
// Block: 64 output pixels x all 256 output channels; 4 waves, wave w owns
// output channels [w*64, w*64+64). K = 2304 ordered kk-major, c-minor.
__global__ __launch_bounds__(256, 4) void mdcn_mfma_kernel(
    const float* __restrict__ x, int Hx, int Wx,
    const float* __restrict__ offs, const float* __restrict__ maskb,
    int Hoff, int Woff, int offstep, int stride,
    const unsigned short* __restrict__ W3, float* __restrict__ y, int Ho, int Wo){
  __shared__ __align__(16) short wlds[8192];     // 16 KB: A tile [256 o][32 kc] swizzled
  __shared__ __align__(16) short colbuf[2048];   // 4 KB:  B tile [64 n][32 kc] swizzled
  __shared__ int4  sAddr[9][64];
  __shared__ float4 sWgt[9][64];

  int t = threadIdx.x;
  int lane = t & 63;
  int wv = t >> 6;
  int HoWo = Ho * Wo;
  int blkPerB = HoWo >> 6;
  int b = blockIdx.x / blkPerB;
  int n0 = (blockIdx.x - b * blkPerB) << 6;
  int HxWx = Hx * Wx;
  int HoffW = Hoff * Woff;

  // ---- precompute bilinear corners + weights (incl. mask) per (kk, n) ----
  for (int idx = t; idx < 576; idx += 256){
    int kk = idx >> 6, n = idx & 63;
    int pix = n0 + n;
    int i = pix / Wo, j = pix - i * Wo;
    int ky = kk / 3, kx = kk - ky * 3;
    int opos = i * offstep * Woff + j * offstep;
    float offy = offs[((long)b * 18 + 2 * kk) * HoffW + opos];
    float offx = offs[((long)b * 18 + 2 * kk + 1) * HoffW + opos];
    float m = maskb[((long)b * 9 + kk) * HoffW + opos];
    float py = (float)(i * stride - 1 + ky) + offy;
    float px = (float)(j * stride - 1 + kx) + offx;
    float y0f = floorf(py), x0f = floorf(px);
    float fy = py - y0f, fx = px - x0f;
    bool vy0 = (y0f >= 0.0f) && (y0f <= (float)(Hx - 1));
    bool vy1 = (y0f + 1.0f >= 0.0f) && (y0f + 1.0f <= (float)(Hx - 1));
    bool vx0 = (x0f >= 0.0f) && (x0f <= (float)(Wx - 1));
    bool vx1 = (x0f + 1.0f >= 0.0f) && (x0f + 1.0f <= (float)(Wx - 1));
    float w0 = (1.0f - fy) * (1.0f - fx) * m * ((vy0 && vx0) ? 1.0f : 0.0f);
    float w1 = (1.0f - fy) * fx * m * ((vy0 && vx1) ? 1.0f : 0.0f);
    float w2 = fy * (1.0f - fx) * m * ((vy1 && vx0) ? 1.0f : 0.0f);
    float w3 = fy * fx * m * ((vy1 && vx1) ? 1.0f : 0.0f);
    int iy0 = min(max((int)y0f, 0), Hx - 1);
    int iy1 = min(max((int)y0f + 1, 0), Hx - 1);
    int ix0 = min(max((int)x0f, 0), Wx - 1);
    int ix1 = min(max((int)x0f + 1, 0), Wx - 1);
    sAddr[kk][n] = make_int4(iy0 * Wx + ix0, iy0 * Wx + ix1, iy1 * Wx + ix0, iy1 * Wx + ix1);
    sWgt[kk][n] = make_float4(w0, w1, w2, w3);
  }
  __syncthreads();

  f32x4 acc[4][4];
  #pragma unroll
  for (int mf = 0; mf < 4; mf++)
    #pragma unroll
    for (int nf = 0; nf < 4; nf++)
      acc[mf][nf] = (f32x4){0.f, 0.f, 0.f, 0.f};

  const char* wb = (const char*)wlds;
  const char* cbuf2 = (const char*)colbuf;

  for (int kk = 0; kk < 9; kk++){
    int4 A4 = sAddr[kk][lane];
    float4 Wt = sWgt[kk][lane];
    for (int cb = 0; cb < 8; cb++){
      __syncthreads();   // previous step's MFMA reads done
      const unsigned short* tile = W3 + (size_t)(kk * 8 + cb) * 8192;
      #pragma unroll
      for (int i = 0; i < 4; i++){
        int q = wv * 4 + i;
        gload_lds16(tile + q * 512 + lane * 8, (void*)(wlds + q * 512));
      }
      const float* xb0 = x + ((long)b * CH + cb * 32 + wv * 8) * HxWx;
      short8 pk;
      #pragma unroll
      for (int j = 0; j < 8; j++){
        const float* xp = xb0 + j * HxWx;
        float v = Wt.x * xp[A4.x] + Wt.y * xp[A4.y] + Wt.z * xp[A4.z] + Wt.w * xp[A4.w];
        pk[j] = (short)f2bf(v);
      }
      *(short8*)((char*)colbuf + lane * 64 + ((wv ^ ((lane >> 1) & 3)) << 4)) = pk;
      __syncthreads();   // drains vmcnt (global_load_lds) + lgkm
      short8 af[4];
      #pragma unroll
      for (int mf = 0; mf < 4; mf++){
        int o = wv * 64 + mf * 16 + (lane & 15);
        af[mf] = *(const short8*)(wb + o * 64 + ((((lane >> 4)) ^ ((o >> 1) & 3)) << 4));
      }
      short8 bfr[4];
      #pragma unroll
      for (int nf = 0; nf < 4; nf++){
        int nc = nf * 16 + (lane & 15);
        bfr[nf] = *(const short8*)(cbuf2 + nc * 64 + ((((lane >> 4)) ^ ((nc >> 1) & 3)) << 4));
      }
      #pragma unroll
      for (int mf = 0; mf < 4; mf++)
        #pragma unroll
        for (int nf = 0; nf < 4; nf++)
          acc[mf][nf] = __builtin_amdgcn_mfma_f32_16x16x32_bf16(af[mf], bfr[nf], acc[mf][nf], 0, 0, 0);
    }
  }

  #pragma unroll
  for (int mf = 0; mf < 4; mf++){
    #pragma unroll
    for (int nf = 0; nf < 4; nf++){
      #pragma unroll
      for (int r = 0; r < 4; r++){
        int o = wv * 64 + mf * 16 + (lane >> 4) * 4 + r;
        int pix = n0 + nf * 16 + (lane & 15);
        y[((long)b * CH + o) * HoWo + pix] = acc[mf][nf][r];
      }
    }
  }
}

// per-(b,c) sums: sum, sumsq, optional weighted sum (rowsum[i]*rowsum[j])
__global__ __launch_bounds__(256) void stats_kernel(
    const float* __restrict__ yv, float* __restrict__ sums, float* __restrict__ sumsq,
    float* __restrict__ wsum, const float* __restrict__ roww, int Hs, int Ws){
  int bc = blockIdx.x;
  int t = threadIdx.x;
  const float* p = yv + (long)bc * Hs * Ws;
  float s = 0, ss = 0, ws = 0;
  int N = Hs * Ws;
  for (int idx = t; idx < N; idx += 256){
    float v = p[idx];
    s += v; ss += v * v;
    if (roww){ int r = idx / Ws, cc = idx - r * Ws; ws += v * roww[r] * roww[cc]; }
  }
  __shared__ float r1[256], r2[256], r3[256];
  r1[t] = s; r2[t] = ss; r3[t] = ws;
  __syncthreads();
  for (int o = 128; o > 0; o >>= 1){
    if (t < o){ r1[t] += r1[t + o]; r2[t] += r2[t + o]; r3[t] += r3[t + o]; }
    __syncthreads();
  }
  if (t == 0){ sums[bc] = r1[0]; sumsq[bc] = r2[0]; if (wsum) wsum[bc] = r3[0]; }
}

__global__ __launch_bounds__(64) void rowsum_kernel(float* __restrict__ roww, int Hh, int H){
  int i = threadIdx.x;
  if (i < Hh){
    float rs = 0.0f;
    float scale = (float)(Hh - 1) / (float)(H - 1);
    for (int h = 0; h < H; h++){
      float ysv = (float)h * scale;
      float y0f = floorf(ysv);
      int y0 = (int)y0f;
      float fy = ysv - y0f;
      int y1 = min(y0 + 1, Hh - 1);
      if (y0 == i) rs += 1.0f - fy;
      if (y1 == i) rs += fy;
    }
    roww[i] = rs;
  }
}

__global__ __launch_bounds__(256) void gn_sa_kernel(
    const float* __restrict__ sums, const float* __restrict__ sumsq,
    const float* __restrict__ psums, float pdiv_inv, float n_inv,
    const float* __restrict__ gw, const float* __restrict__ gb,
    const float* __restrict__ saw, const float* __restrict__ sab,
    float* __restrict__ mu_o, float* __restrict__ rs_o, float* __restrict__ v_o){
  int b = blockIdx.x; int t = threadIdx.x;
  __shared__ float smu[GRP], srs[GRP], red[256];
  if (t < GRP){
    float s = 0, ss = 0;
    for (int c = 0; c < 16; c++){ int idx = b * CH + t * 16 + c; s += sums[idx]; ss += sumsq[idx]; }
    float mu = s * n_inv;
    float var = ss * n_inv - mu * mu;
    float rs = rsqrtf(var + EPSV);
    smu[t] = mu; srs[t] = rs;
    mu_o[b * GRP + t] = mu; rs_o[b * GRP + t] = rs;
  }
  __syncthreads();
  int g = t >> 4;
  float pm = (psums[b * CH + t] * pdiv_inv - smu[g]) * srs[g] * gw[t] + gb[t];
  red[t] = pm * saw[t];
  __syncthreads();
  for (int o = 128; o > 0; o >>= 1){ if (t < o) red[t] += red[t + o]; __syncthreads(); }
  if (t == 0) v_o[b] = hsig(fmaxf(red[0] + sab[0], 0.0f));
}

__global__ __launch_bounds__(256) void combine_kernel(
    float* __restrict__ smid, const float* __restrict__ ylo, const float* __restrict__ yhi,
    const float* __restrict__ mu_m, const float* __restrict__ rs_m, const float* __restrict__ gw_m, const float* __restrict__ gb_m, const float* __restrict__ v_m,
    const float* __restrict__ mu_l, const float* __restrict__ rs_l, const float* __restrict__ gw_l, const float* __restrict__ gb_l, const float* __restrict__ v_l,
    const float* __restrict__ mu_h, const float* __restrict__ rs_h, const float* __restrict__ gw_h, const float* __restrict__ gb_h, const float* __restrict__ v_h,
    int H, int W, int has_lo, int has_hi, float inv_cnt){
  int idx = blockIdx.x * 256 + threadIdx.x;
  int HW = H * W;
  int b = idx / (CH * HW);
  int r1 = idx - b * CH * HW;
  int c = r1 / HW;
  int rem = r1 - c * HW;
  int h = rem / W;
  int w = rem - h * W;
  int g = c >> 4;
  int bg = b * GRP + g;
  float s = v_m[b] * ((smid[idx] - mu_m[bg]) * rs_m[bg] * gw_m[c] + gb_m[c]);
  if (has_lo) s += v_l[b] * ((ylo[idx] - mu_l[bg]) * rs_l[bg] * gw_l[c] + gb_l[c]);
  if (has_hi){
    int Hh = H >> 1, Wh = W >> 1;
    float ysv = (float)h * ((float)(Hh - 1) / (float)(H - 1));
    float y0f = floorf(ysv); int y0 = (int)y0f; float fy = ysv - y0f; int y1 = min(y0 + 1, Hh - 1);
    float xsv = (float)w * ((float)(Wh - 1) / (float)(W - 1));
    float x0f = floorf(xsv); int x0 = (int)x0f; float fx = xsv - x0f; int x1 = min(x0 + 1, Wh - 1);
    const float* hb = yhi + (b * CH + c) * Hh * Wh;
    float v00 = hb[y0 * Wh + x0], v01 = hb[y0 * Wh + x1];
    float v10 = hb[y1 * Wh + x0], v11 = hb[y1 * Wh + x1];
    float bl = v00 * (1 - fy) * (1 - fx) + v01 * (1 - fy) * fx + v10 * fy * (1 - fx) + v11 * fy * fx;
    s += v_h[b] * ((bl - mu_h[bg]) * rs_h[bg] * gw_h[c] + gb_h[c]);
  }
  smid[idx] = s * inv_cnt;
}

__global__ __launch_bounds__(256) void dyrelu_coef_kernel(
    const float* __restrict__ psum, float inv_hw,
    const float* __restrict__ w1, const float* __restrict__ b1,
    const float* __restrict__ w2, const float* __restrict__ b2,
    float* __restrict__ coef){
  int b = blockIdx.x; int t = threadIdx.x;
  __shared__ float pl[CH], hl[64];
  pl[t] = psum[b * CH + t] * inv_hw;
  __syncthreads();
  if (t < 64){
    float a = b1[t];
    const float* wr = w1 + t * CH;
    for (int c = 0; c < CH; c++) a += wr[c] * pl[c];
    hl[t] = fmaxf(a, 0.0f);
  }
  __syncthreads();
  #pragma unroll
  for (int r = 0; r < 4; r++){
    int o = r * CH + t;
    float a = b2[o];
    const float* wr = w2 + o * 64;
    #pragma unroll
    for (int j = 0; j < 64; j++) a += wr[j] * hl[j];
    float co = hsig(a) - 0.5f;
    float outv;
    if (r == 0) outv = co * 2.0f + 1.0f;
    else if (r == 2) outv = co * 2.0f;
    else outv = co;
    coef[(b * 4 + r) * CH + t] = outv;
  }
}

__global__ __launch_bounds__(256) void final_kernel(
    const float* __restrict__ s, const float* __restrict__ coef, float* __restrict__ outp, int HW){
  int idx = blockIdx.x * 256 + threadIdx.x;
  int b = idx / (CH * HW);
  int c = (idx - b * CH * HW) / HW;
  const float* cf = coef + b * 4 * CH;
  float a1 = cf[c], c1 = cf[CH + c], a2 = cf[2 * CH + c], c2 = cf[3 * CH + c];
  float xv = s[idx];
  outp[idx] = fmaxf(xv * a1 + c1, xv * a2 + c2);
}

extern "C" void kernel_launch(void* const* d_in, const int* in_sizes, int n_in,
                              void* d_out, int out_size, void* d_ws, size_t ws_size,
                              hipStream_t stream){
  const float* x[3] = {(const float*)d_in[0], (const float*)d_in[1], (const float*)d_in[2]};
  const float* w_off = (const float*)d_in[3];
  const float* b_off = (const float*)d_in[4];
  int sig = (in_sizes[6] == 256);
  const float* w_high = (const float*)d_in[5];
  const float* w_mid  = (const float*)d_in[sig ? 8 : 6];
  const float* w_low  = (const float*)d_in[sig ? 11 : 7];
  const float* gn_high_w = (const float*)d_in[sig ? 6 : 8];
  const float* gn_high_b = (const float*)d_in[sig ? 7 : 9];
  const float* gn_mid_w  = (const float*)d_in[sig ? 9 : 10];
  const float* gn_mid_b  = (const float*)d_in[sig ? 10 : 11];
  const float* gn_low_w  = (const float*)d_in[12];
  const float* gn_low_b  = (const float*)d_in[13];
  const float* sa_w  = (const float*)d_in[14];
  const float* sa_b  = (const float*)d_in[15];
  const float* dy_w1 = (const float*)d_in[16];
  const float* dy_b1 = (const float*)d_in[17];
  const float* dy_w2 = (const float*)d_in[18];
  const float* dy_b2 = (const float*)d_in[19];

  float* p = (float*)d_ws;
  unsigned short* W3_mid  = (unsigned short*)p; p += 589824;
  unsigned short* W3_low  = (unsigned short*)p; p += 589824;
  unsigned short* W3_high = (unsigned short*)p; p += 589824;
  unsigned short* W27     = (unsigned short*)p; p += 36864;
  float* offs    = p; p += 294912;
  float* maskb   = p; p += 147456;
  float* y_mid   = p; p += 4194304;
  float* y_lo    = p; p += 1048576;
  float* y_hi    = p; p += 1048576;
  float* sum_m = p; p += 1024;  float* ss_m = p; p += 1024;
  float* sum_l = p; p += 1024;  float* ss_l = p; p += 1024;
  float* sum_h = p; p += 1024;  float* ss_h = p; p += 1024;
  float* wsum_h = p; p += 1024;
  float* psum   = p; p += 1024;
  float* mu_m = p; p += 64;  float* rs_m = p; p += 64;
  float* mu_l = p; p += 64;  float* rs_l = p; p += 64;
  float* mu_h = p; p += 64;  float* rs_h = p; p += 64;
  float* v_m = p; p += 16;   float* v_l = p; p += 16;  float* v_h = p; p += 16;
  float* roww = p; p += 64;
  float* coefb = p; p += 4096;

  pack_w_kernel<<<2304, 256, 0, stream>>>(w_mid,  W3_mid);
  pack_w_kernel<<<2304, 256, 0, stream>>>(w_low,  W3_low);
  pack_w_kernel<<<2304, 256, 0, stream>>>(w_high, W3_high);
  pack_woff_kernel<<<288, 256, 0, stream>>>(w_off, W27);

  long out_off = 0;
  for (int lvl = 0; lvl < 3; lvl++){
    int H = 64 >> lvl, W = H;
    int HW = H * W;
    int has_lo = (lvl > 0) ? 1 : 0;
    int has_hi = (lvl < 2) ? 1 : 0;

    conv_offset_mfma_kernel<<<BB * HW / 256, 256, 0, stream>>>(x[lvl], W27, b_off, offs, maskb, H, W);

    mdcn_mfma_kernel<<<BB * HW / 64, 256, 0, stream>>>(x[lvl], H, W, offs, maskb, H, W, 1, 1, W3_mid, y_mid, H, W);
    if (has_lo)
      mdcn_mfma_kernel<<<BB * HW / 64, 256, 0, stream>>>(x[lvl - 1], 2 * H, 2 * W, offs, maskb, H, W, 1, 2, W3_low, y_lo, H, W);
    if (has_hi)
      mdcn_mfma_kernel<<<BB * (HW / 4) / 64, 256, 0, stream>>>(x[lvl + 1], H / 2, W / 2, offs, maskb, H, W, 2, 1, W3_high, y_hi, H / 2, W / 2);

    stats_kernel<<<BB * CH, 256, 0, stream>>>(y_mid, sum_m, ss_m, nullptr, nullptr, H, W);
    if (has_lo) stats_kernel<<<BB * CH, 256, 0, stream>>>(y_lo, sum_l, ss_l, nullptr, nullptr, H, W);
    if (has_hi){
      rowsum_kernel<<<1, 64, 0, stream>>>(roww, H / 2, H);
      stats_kernel<<<BB * CH, 256, 0, stream>>>(y_hi, sum_h, ss_h, wsum_h, roww, H / 2, W / 2);
    }

    float invHW = 1.0f / (float)HW;
    gn_sa_kernel<<<BB, 256, 0, stream>>>(sum_m, ss_m, sum_m, invHW, 1.0f / (16.0f * HW),
                                         gn_mid_w, gn_mid_b, sa_w, sa_b, mu_m, rs_m, v_m);
    if (has_lo)
      gn_sa_kernel<<<BB, 256, 0, stream>>>(sum_l, ss_l, sum_l, invHW, 1.0f / (16.0f * HW),
                                           gn_low_w, gn_low_b, sa_w, sa_b, mu_l, rs_l, v_l);
    if (has_hi)
      gn_sa_kernel<<<BB, 256, 0, stream>>>(sum_h, ss_h, wsum_h, invHW, 1.0f / (16.0f * (HW / 4)),
                                           gn_high_w, gn_high_b, sa_w, sa_b, mu_h, rs_h, v_h);

    float cnt = 1.0f + (float)has_lo + (float)has_hi;
    combine_kernel<<<BB * CH * HW / 256, 256, 0, stream>>>(
        y_mid, y_lo, y_hi,
        mu_m, rs_m, gn_mid_w, gn_mid_b, v_m,
        mu_l, rs_l, gn_low_w, gn_low_b, v_l,
        mu_h, rs_h, gn_high_w, gn_high_b, v_h,
        H, W, has_lo, has_hi, 1.0f / cnt);

    stats_kernel<<<BB * CH, 256, 0, stream>>>(y_mid, psum, ss_m, nullptr, nullptr, H, W);
    dyrelu_coef_kernel<<<BB, 256, 0, stream>>>(psum, invHW, dy_w1, dy_b1, dy_w2, dy_b2, coefb);
    final_kernel<<<BB * CH * HW / 256, 256, 0, stream>>>(y_mid, coefb, (float*)d_out + out_off, HW);
    out_off += (long)BB * CH * HW;
  }
}

// Round 4
// 393.999 us; speedup vs baseline: 10.3912x; 5.1412x over previous
//
#include <hip/hip_runtime.h>
#include <math.h>

#define CH 256
#define GRP 16
#define EPSV 1e-5f
#define BB 4

typedef __attribute__((ext_vector_type(8))) short short8;
typedef __attribute__((ext_vector_type(4))) float f32x4;

__device__ __forceinline__ float hsig(float x){
  return fminf(fmaxf((x + 3.0f) * (1.0f/6.0f), 0.0f), 1.0f);
}

__device__ __forceinline__ unsigned short f2bf(float f){
  union { float f; unsigned int u; } v; v.f = f;
  unsigned int r = v.u + 0x7fffu + ((v.u >> 16) & 1u);
  return (unsigned short)(r >> 16);
}

__device__ __forceinline__ void gload_lds16(const void* g, void* l){
  __builtin_amdgcn_global_load_lds((const __attribute__((address_space(1))) unsigned int*)g,
                                   (__attribute__((address_space(3))) unsigned int*)l, 16, 0, 0);
}

// ---------------- weight packing (pre-swizzled bf16 K-step tiles) -------------
__global__ __launch_bounds__(256) void pack_w_kernel(const float* __restrict__ w, unsigned short* __restrict__ W3){
  int idx = blockIdx.x * 256 + threadIdx.x;   // 0..589823
  int s = idx >> 13;
  int r = idx & 8191;
  int o = r >> 5;
  int pos = r & 31;
  int cp = pos >> 3, j = pos & 7;
  int kc = ((cp ^ ((o >> 1) & 3)) << 3) + j;
  int kk = s >> 3, cb = s & 7;
  int c = (cb << 5) + kc;
  W3[idx] = f2bf(w[((o << 8) + c) * 9 + kk]);
}

__global__ __launch_bounds__(256) void pack_woff_kernel(const float* __restrict__ w, unsigned short* __restrict__ W27){
  int idx = blockIdx.x * 256 + threadIdx.x;   // 0..73727
  int s = idx >> 10;
  int r = idx & 1023;
  int o = r >> 5;
  int pos = r & 31;
  int cp = pos >> 3, j = pos & 7;
  int kc = ((cp ^ ((o >> 1) & 3)) << 3) + j;
  int kk = s >> 3, cb = s & 7;
  int c = (cb << 5) + kc;
  W27[idx] = (o < 27) ? f2bf(w[(o * CH + c) * 9 + kk]) : (unsigned short)0;
}

// ---------------- NCHW -> NHWC transpose, all 3 levels fused ------------------
__global__ __launch_bounds__(256) void nhwc_kernel(
    const float* __restrict__ x0, const float* __restrict__ x1, const float* __restrict__ x2,
    float* __restrict__ xn0, float* __restrict__ xn1, float* __restrict__ xn2){
  __shared__ float lds[32][257];
  int blk = blockIdx.x;
  const float* xs; float* xd; int HW; int rb;
  if (blk < 512){ xs = x0; xd = xn0; HW = 4096; rb = blk; }
  else if (blk < 640){ xs = x1; xd = xn1; HW = 1024; rb = blk - 512; }
  else { xs = x2; xd = xn2; HW = 256; rb = blk - 640; }
  int p0 = rb * 32;
  int b = p0 / HW;
  int rem0 = p0 - b * HW;
  int t = threadIdx.x;
  int pl = t & 31, cg = t >> 5;
  for (int ci = 0; ci < 32; ci++){
    int c = ci * 8 + cg;
    lds[pl][c] = xs[(long)(b * CH + c) * HW + rem0 + pl];
  }
  __syncthreads();
  for (int p = 0; p < 32; p++){
    xd[(long)(b * HW + rem0 + p) * CH + t] = lds[p][t];
  }
}

// ---------------- upsample row-weight tables (both level transitions) ---------
__global__ __launch_bounds__(64) void rowsum2_kernel(float* __restrict__ roww0, float* __restrict__ roww1){
  int blk = blockIdx.x;
  float* out = blk ? roww1 : roww0;
  int Hh = blk ? 16 : 32;
  int H = blk ? 32 : 64;
  int i = threadIdx.x;
  if (i < Hh){
    float rs = 0.0f;
    float scale = (float)(Hh - 1) / (float)(H - 1);
    for (int h = 0; h < H; h++){
      float ysv = (float)h * scale;
      float y0f = floorf(ysv);
      int y0 = (int)y0f;
      float fy = ysv - y0f;
      int y1 = min(y0 + 1, Hh - 1);
      if (y0 == i) rs += 1.0f - fy;
      if (y1 == i) rs += fy;
    }
    out[i] = rs;
  }
}

// ---------------- offset conv (all levels fused), im2col + MFMA, M=32 ---------
// Block: 64 px, 256 threads; B tile [64px][32ch] shared; wave wv owns px frag wv*16.
__global__ __launch_bounds__(256, 4) void conv_offset_mfma_kernel(
    const float* __restrict__ xn0, const float* __restrict__ xn1, const float* __restrict__ xn2,
    const unsigned short* __restrict__ W27, const float* __restrict__ boff,
    float* __restrict__ offs_all, float* __restrict__ mask_all){
  __shared__ __align__(16) short awlds[1024];   // 2 KB A [32][32]
  __shared__ __align__(16) short cbuf[4096];    // 8 KB B [64][32]
  int blk = blockIdx.x;
  const float* xn; int H; long ooff, moff; int rb;
  if (blk < 256){ xn = xn0; H = 64; ooff = 0; moff = 0; rb = blk; }
  else if (blk < 320){ xn = xn1; H = 32; ooff = 294912; moff = 147456; rb = blk - 256; }
  else { xn = xn2; H = 16; ooff = 368640; moff = 184320; rb = blk - 320; }
  int W = H, HW = H * W;
  int t = threadIdx.x;
  int lane = t & 63, wv = t >> 6;
  int pg = rb * 64 + lane;
  int b = pg / HW;
  int rem = pg - b * HW;
  int i = rem / W, j = rem - i * W;

  f32x4 acc[2];
  #pragma unroll
  for (int mf = 0; mf < 2; mf++){
    #pragma unroll
    for (int r = 0; r < 4; r++){
      int o = mf * 16 + (lane >> 4) * 4 + r;
      acc[mf][r] = boff[o < 27 ? o : 0];
    }
  }

  for (int kk = 0; kk < 9; kk++){
    int ky = kk / 3, kx = kk - ky * 3;
    int ii = i - 1 + ky, jj = j - 1 + kx;
    bool valid = (ii >= 0 && ii < H && jj >= 0 && jj < W);
    int addr = valid ? ((b * HW + ii * W + jj) << 8) : 0;
    float vm = valid ? 1.0f : 0.0f;
    for (int cb8 = 0; cb8 < 8; cb8++){
      __syncthreads();
      const unsigned short* tile = W27 + (size_t)(kk * 8 + cb8) * 1024;
      if (t < 128) gload_lds16(tile + (t >> 6) * 512 + (t & 63) * 8, (short*)awlds + (t >> 6) * 512);
      const float* xc = xn + addr + cb8 * 32 + wv * 8;
      float4 va = *(const float4*)xc;
      float4 vb = *(const float4*)(xc + 4);
      short8 pk;
      pk[0] = (short)f2bf(vm * va.x); pk[1] = (short)f2bf(vm * va.y);
      pk[2] = (short)f2bf(vm * va.z); pk[3] = (short)f2bf(vm * va.w);
      pk[4] = (short)f2bf(vm * vb.x); pk[5] = (short)f2bf(vm * vb.y);
      pk[6] = (short)f2bf(vm * vb.z); pk[7] = (short)f2bf(vm * vb.w);
      *(short8*)((char*)cbuf + lane * 64 + ((wv ^ ((lane >> 1) & 3)) << 4)) = pk;
      __syncthreads();
      short8 af[2];
      #pragma unroll
      for (int mf = 0; mf < 2; mf++){
        int o = mf * 16 + (lane & 15);
        af[mf] = *(const short8*)((const char*)awlds + o * 64 + ((((lane >> 4)) ^ ((o >> 1) & 3)) << 4));
      }
      int nc = wv * 16 + (lane & 15);
      short8 bf1 = *(const short8*)((const char*)cbuf + nc * 64 + ((((lane >> 4)) ^ ((nc >> 1) & 3)) << 4));
      acc[0] = __builtin_amdgcn_mfma_f32_16x16x32_bf16(af[0], bf1, acc[0], 0, 0, 0);
      acc[1] = __builtin_amdgcn_mfma_f32_16x16x32_bf16(af[1], bf1, acc[1], 0, 0, 0);
    }
  }

  int rem0 = rb * 64 - b * HW;
  #pragma unroll
  for (int mf = 0; mf < 2; mf++){
    #pragma unroll
    for (int r = 0; r < 4; r++){
      int o = mf * 16 + (lane >> 4) * 4 + r;
      int pix = rem0 + wv * 16 + (lane & 15);
      float v = acc[mf][r];
      if (o < 18) offs_all[ooff + ((long)b * 18 + o) * HW + pix] = v;
      else if (o < 27) mask_all[moff + ((long)b * 9 + (o - 18)) * HW + pix] = 1.0f / (1.0f + expf(-v));
    }
  }
}

// ---------------- mdcn: all 7 jobs fused, NHWC gather + MFMA ------------------
__device__ const int MJ_start[8] = {0,256,320,384,448,464,480,496};
__device__ const int MJ_xsel[7]  = {0,1,1,0,2,2,1};
__device__ const int MJ_Hx[7]    = {64,32,32,64,16,16,32};
__device__ const int MJ_ooff[7]  = {0,0,294912,294912,294912,368640,368640};
__device__ const int MJ_moff[7]  = {0,0,147456,147456,147456,184320,184320};
__device__ const int MJ_Hoff[7]  = {64,64,32,32,32,16,16};
__device__ const int MJ_ostep[7] = {1,2,1,1,2,1,1};
__device__ const int MJ_strd[7]  = {1,1,1,2,1,1,2};
__device__ const int MJ_wsel[7]  = {0,2,0,1,2,0,1};
__device__ const int MJ_yoff[7]  = {0,4194304,5242880,6291456,7340032,7602176,7864320};
__device__ const int MJ_Ho[7]    = {64,32,32,32,16,16,16};

__global__ __launch_bounds__(256, 4) void mdcn_mfma_kernel(
    const float* __restrict__ xn0, const float* __restrict__ xn1, const float* __restrict__ xn2,
    const float* __restrict__ offs_all, const float* __restrict__ mask_all,
    const unsigned short* __restrict__ Wm, const unsigned short* __restrict__ Wl, const unsigned short* __restrict__ Wh,
    float* __restrict__ y_all){
  __shared__ __align__(16) short wlds[8192];     // 16 KB A [256][32]
  __shared__ __align__(16) short colbuf[2048];   // 4 KB  B [64][32]
  __shared__ int4  sAddr[9][64];
  __shared__ float4 sWgt[9][64];

  int blk = blockIdx.x;
  int job = 0;
  while (job < 6 && blk >= MJ_start[job + 1]) job++;
  int xsel = MJ_xsel[job];
  const float* xn = (xsel == 0) ? xn0 : (xsel == 1 ? xn1 : xn2);
  int wsel = MJ_wsel[job];
  const unsigned short* W3 = (wsel == 0) ? Wm : (wsel == 1 ? Wl : Wh);
  int Hx = MJ_Hx[job], Wx = Hx, HxWx = Hx * Hx;
  int Ho = MJ_Ho[job], Wo = Ho, HoWo = Ho * Ho;
  int Woff = MJ_Hoff[job], HoffW = Woff * Woff;
  int ostep = MJ_ostep[job], stride = MJ_strd[job];
  const float* offs = offs_all + MJ_ooff[job];
  const float* maskb = mask_all + MJ_moff[job];
  float* y = y_all + MJ_yoff[job];

  int rb = blk - MJ_start[job];
  int blkPerB = HoWo >> 6;
  int b = rb / blkPerB;
  int n0 = (rb - b * blkPerB) << 6;

  int t = threadIdx.x;
  int lane = t & 63;
  int wv = t >> 6;

  for (int idx = t; idx < 576; idx += 256){
    int kk = idx >> 6, n = idx & 63;
    int pix = n0 + n;
    int i = pix / Wo, j = pix - i * Wo;
    int ky = kk / 3, kx = kk - ky * 3;
    int opos = i * ostep * Woff + j * ostep;
    float offy = offs[((long)b * 18 + 2 * kk) * HoffW + opos];
    float offx = offs[((long)b * 18 + 2 * kk + 1) * HoffW + opos];
    float m = maskb[((long)b * 9 + kk) * HoffW + opos];
    float py = (float)(i * stride - 1 + ky) + offy;
    float px = (float)(j * stride - 1 + kx) + offx;
    float y0f = floorf(py), x0f = floorf(px);
    float fy = py - y0f, fx = px - x0f;
    bool vy0 = (y0f >= 0.0f) && (y0f <= (float)(Hx - 1));
    bool vy1 = (y0f + 1.0f >= 0.0f) && (y0f + 1.0f <= (float)(Hx - 1));
    bool vx0 = (x0f >= 0.0f) && (x0f <= (float)(Wx - 1));
    bool vx1 = (x0f + 1.0f >= 0.0f) && (x0f + 1.0f <= (float)(Wx - 1));
    float w0 = (1.0f - fy) * (1.0f - fx) * m * ((vy0 && vx0) ? 1.0f : 0.0f);
    float w1 = (1.0f - fy) * fx * m * ((vy0 && vx1) ? 1.0f : 0.0f);
    float w2 = fy * (1.0f - fx) * m * ((vy1 && vx0) ? 1.0f : 0.0f);
    float w3 = fy * fx * m * ((vy1 && vx1) ? 1.0f : 0.0f);
    int iy0 = min(max((int)y0f, 0), Hx - 1);
    int iy1 = min(max((int)y0f + 1, 0), Hx - 1);
    int ix0 = min(max((int)x0f, 0), Wx - 1);
    int ix1 = min(max((int)x0f + 1, 0), Wx - 1);
    int base = b * HxWx;
    sAddr[kk][n] = make_int4((base + iy0 * Wx + ix0) << 8, (base + iy0 * Wx + ix1) << 8,
                             (base + iy1 * Wx + ix0) << 8, (base + iy1 * Wx + ix1) << 8);
    sWgt[kk][n] = make_float4(w0, w1, w2, w3);
  }
  __syncthreads();

  f32x4 acc[4][4];
  #pragma unroll
  for (int mf = 0; mf < 4; mf++)
    #pragma unroll
    for (int nf = 0; nf < 4; nf++)
      acc[mf][nf] = (f32x4){0.f, 0.f, 0.f, 0.f};

  for (int kk = 0; kk < 9; kk++){
    int4 A4 = sAddr[kk][lane];
    float4 Wt = sWgt[kk][lane];
    for (int cb = 0; cb < 8; cb++){
      __syncthreads();   // previous step's MFMA reads done
      const unsigned short* tile = W3 + (size_t)(kk * 8 + cb) * 8192;
      #pragma unroll
      for (int i2 = 0; i2 < 4; i2++){
        int q = wv * 4 + i2;
        gload_lds16(tile + q * 512 + lane * 8, (void*)(wlds + q * 512));
      }
      const float* xc = xn + cb * 32 + wv * 8;
      const float4* q0 = (const float4*)(xc + A4.x);
      const float4* q1 = (const float4*)(xc + A4.y);
      const float4* q2 = (const float4*)(xc + A4.z);
      const float4* q3 = (const float4*)(xc + A4.w);
      float4 a0 = q0[0], e0 = q0[1];
      float4 a1 = q1[0], e1 = q1[1];
      float4 a2 = q2[0], e2 = q2[1];
      float4 a3 = q3[0], e3 = q3[1];
      short8 pk;
      pk[0] = (short)f2bf(Wt.x*a0.x + Wt.y*a1.x + Wt.z*a2.x + Wt.w*a3.x);
      pk[1] = (short)f2bf(Wt.x*a0.y + Wt.y*a1.y + Wt.z*a2.y + Wt.w*a3.y);
      pk[2] = (short)f2bf(Wt.x*a0.z + Wt.y*a1.z + Wt.z*a2.z + Wt.w*a3.z);
      pk[3] = (short)f2bf(Wt.x*a0.w + Wt.y*a1.w + Wt.z*a2.w + Wt.w*a3.w);
      pk[4] = (short)f2bf(Wt.x*e0.x + Wt.y*e1.x + Wt.z*e2.x + Wt.w*e3.x);
      pk[5] = (short)f2bf(Wt.x*e0.y + Wt.y*e1.y + Wt.z*e2.y + Wt.w*e3.y);
      pk[6] = (short)f2bf(Wt.x*e0.z + Wt.y*e1.z + Wt.z*e2.z + Wt.w*e3.z);
      pk[7] = (short)f2bf(Wt.x*e0.w + Wt.y*e1.w + Wt.z*e2.w + Wt.w*e3.w);
      *(short8*)((char*)colbuf + lane * 64 + ((wv ^ ((lane >> 1) & 3)) << 4)) = pk;
      __syncthreads();
      short8 af[4];
      #pragma unroll
      for (int mf = 0; mf < 4; mf++){
        int o = wv * 64 + mf * 16 + (lane & 15);
        af[mf] = *(const short8*)((const char*)wlds + o * 64 + ((((lane >> 4)) ^ ((o >> 1) & 3)) << 4));
      }
      short8 bfr[4];
      #pragma unroll
      for (int nf = 0; nf < 4; nf++){
        int nc = nf * 16 + (lane & 15);
        bfr[nf] = *(const short8*)((const char*)colbuf + nc * 64 + ((((lane >> 4)) ^ ((nc >> 1) & 3)) << 4));
      }
      #pragma unroll
      for (int mf = 0; mf < 4; mf++)
        #pragma unroll
        for (int nf = 0; nf < 4; nf++)
          acc[mf][nf] = __builtin_amdgcn_mfma_f32_16x16x32_bf16(af[mf], bfr[nf], acc[mf][nf], 0, 0, 0);
    }
  }

  #pragma unroll
  for (int mf = 0; mf < 4; mf++){
    #pragma unroll
    for (int nf = 0; nf < 4; nf++){
      #pragma unroll
      for (int r = 0; r < 4; r++){
        int o = wv * 64 + mf * 16 + (lane >> 4) * 4 + r;
        int pix = n0 + nf * 16 + (lane & 15);
        y[((long)b * CH + o) * HoWo + pix] = acc[mf][nf][r];
      }
    }
  }
}

// ---------------- stats over all 7 tensors, fused -----------------------------
__device__ const int SJ_yoff[7] = {0,4194304,5242880,6291456,7340032,7602176,7864320};
__device__ const int SJ_HW[7]   = {4096,1024,1024,1024,256,256,256};
__device__ const int SJ_rw[7]   = {0,1,0,0,2,0,0};

__global__ __launch_bounds__(256) void stats_all_kernel(
    const float* __restrict__ y_all, const float* __restrict__ roww0, const float* __restrict__ roww1,
    float* __restrict__ sums_all, float* __restrict__ ss_all, float* __restrict__ wsum_all){
  int blk = blockIdx.x;
  int job = blk >> 10, bc = blk & 1023;
  int HW = SJ_HW[job];
  int Ws = (HW == 4096) ? 64 : ((HW == 1024) ? 32 : 16);
  int rwsel = SJ_rw[job];
  const float* rw = (rwsel == 2) ? roww1 : roww0;
  const float* p = y_all + SJ_yoff[job] + (long)bc * HW;
  int t = threadIdx.x;
  float s = 0, ss = 0, ws = 0;
  for (int idx = t; idx < HW; idx += 256){
    float v = p[idx];
    s += v; ss += v * v;
    if (rwsel){ int r = idx / Ws, cc = idx - r * Ws; ws += v * rw[r] * rw[cc]; }
  }
  __shared__ float r1[256], r2[256], r3[256];
  r1[t] = s; r2[t] = ss; r3[t] = ws;
  __syncthreads();
  for (int o = 128; o > 0; o >>= 1){
    if (t < o){ r1[t] += r1[t + o]; r2[t] += r2[t + o]; r3[t] += r3[t + o]; }
    __syncthreads();
  }
  if (t == 0){
    sums_all[job * 1024 + bc] = r1[0];
    ss_all[job * 1024 + bc] = r2[0];
    if (rwsel) wsum_all[(rwsel - 1) * 1024 + bc] = r3[0];
  }
}

// ---------------- group-norm stats + scale_attn, all 7 jobs fused -------------
__device__ const int   GJ_psrc[7] = {0,1,0,0,2,0,0};
__device__ const float GJ_pdiv[7] = {1.f/4096,1.f/4096,1.f/1024,1.f/1024,1.f/1024,1.f/256,1.f/256};
__device__ const float GJ_ninv[7] = {1.f/65536,1.f/16384,1.f/16384,1.f/16384,1.f/4096,1.f/4096,1.f/4096};
__device__ const int   GJ_gsel[7] = {0,2,0,1,2,0,1};

__global__ __launch_bounds__(256) void gn_sa_all_kernel(
    const float* __restrict__ sums_all, const float* __restrict__ ss_all, const float* __restrict__ wsum_all,
    const float* __restrict__ gw_m, const float* __restrict__ gb_m,
    const float* __restrict__ gw_l, const float* __restrict__ gb_l,
    const float* __restrict__ gw_h, const float* __restrict__ gb_h,
    const float* __restrict__ saw, const float* __restrict__ sab,
    float* __restrict__ mu_all, float* __restrict__ rs_all, float* __restrict__ v_all){
  int blk = blockIdx.x;
  int job = blk >> 2, b = blk & 3;
  int t = threadIdx.x;
  const float* sums = sums_all + job * 1024;
  const float* ssq  = ss_all + job * 1024;
  int psrc = GJ_psrc[job];
  const float* ps = (psrc == 0) ? sums : (wsum_all + (psrc - 1) * 1024);
  int gsel = GJ_gsel[job];
  const float* gw = (gsel == 0) ? gw_m : (gsel == 1 ? gw_l : gw_h);
  const float* gb = (gsel == 0) ? gb_m : (gsel == 1 ? gb_l : gb_h);
  float pdiv = GJ_pdiv[job], ninv = GJ_ninv[job];
  __shared__ float smu[GRP], srs[GRP], red[256];
  if (t < GRP){
    float s = 0, ss = 0;
    for (int c = 0; c < 16; c++){ int idx = b * CH + t * 16 + c; s += sums[idx]; ss += ssq[idx]; }
    float mu = s * ninv;
    float var = ss * ninv - mu * mu;
    float rs = rsqrtf(var + EPSV);
    smu[t] = mu; srs[t] = rs;
    mu_all[job * 64 + b * GRP + t] = mu;
    rs_all[job * 64 + b * GRP + t] = rs;
  }
  __syncthreads();
  int g = t >> 4;
  float pm = (ps[b * CH + t] * pdiv - smu[g]) * srs[g] * gw[t] + gb[t];
  red[t] = pm * saw[t];
  __syncthreads();
  for (int o = 128; o > 0; o >>= 1){ if (t < o) red[t] += red[t + o]; __syncthreads(); }
  if (t == 0) v_all[job * 4 + b] = hsig(fmaxf(red[0] + sab[0], 0.0f));
}

// ---------------- combine (GN + scale_attn + upsample), per level -------------
__global__ __launch_bounds__(256) void combine_kernel(
    float* __restrict__ smid, const float* __restrict__ ylo, const float* __restrict__ yhi,
    const float* __restrict__ mu_m, const float* __restrict__ rs_m, const float* __restrict__ gw_m, const float* __restrict__ gb_m, const float* __restrict__ v_m,
    const float* __restrict__ mu_l, const float* __restrict__ rs_l, const float* __restrict__ gw_l, const float* __restrict__ gb_l, const float* __restrict__ v_l,
    const float* __restrict__ mu_h, const float* __restrict__ rs_h, const float* __restrict__ gw_h, const float* __restrict__ gb_h, const float* __restrict__ v_h,
    int H, int W, int has_lo, int has_hi, float inv_cnt){
  int idx = blockIdx.x * 256 + threadIdx.x;
  int HW = H * W;
  int b = idx / (CH * HW);
  int r1 = idx - b * CH * HW;
  int c = r1 / HW;
  int rem = r1 - c * HW;
  int h = rem / W;
  int w = rem - h * W;
  int g = c >> 4;
  int bg = b * GRP + g;
  float s = v_m[b] * ((smid[idx] - mu_m[bg]) * rs_m[bg] * gw_m[c] + gb_m[c]);
  if (has_lo) s += v_l[b] * ((ylo[idx] - mu_l[bg]) * rs_l[bg] * gw_l[c] + gb_l[c]);
  if (has_hi){
    int Hh = H >> 1, Wh = W >> 1;
    float ysv = (float)h * ((float)(Hh - 1) / (float)(H - 1));
    float y0f = floorf(ysv); int y0 = (int)y0f; float fy = ysv - y0f; int y1 = min(y0 + 1, Hh - 1);
    float xsv = (float)w * ((float)(Wh - 1) / (float)(W - 1));
    float x0f = floorf(xsv); int x0 = (int)x0f; float fx = xsv - x0f; int x1 = min(x0 + 1, Wh - 1);
    const float* hb = yhi + (b * CH + c) * Hh * Wh;
    float v00 = hb[y0 * Wh + x0], v01 = hb[y0 * Wh + x1];
    float v10 = hb[y1 * Wh + x0], v11 = hb[y1 * Wh + x1];
    float bl = v00 * (1 - fy) * (1 - fx) + v01 * (1 - fy) * fx + v10 * fy * (1 - fx) + v11 * fy * fx;
    s += v_h[b] * ((bl - mu_h[bg]) * rs_h[bg] * gw_h[c] + gb_h[c]);
  }
  smid[idx] = s * inv_cnt;
}

// ---------------- per-(b,c) plane sums (for dyrelu), per level ----------------
__global__ __launch_bounds__(256) void stats_kernel(
    const float* __restrict__ yv, float* __restrict__ sums, float* __restrict__ sumsq, int N){
  int bc = blockIdx.x;
  int t = threadIdx.x;
  const float* p = yv + (long)bc * N;
  float s = 0, ss = 0;
  for (int idx = t; idx < N; idx += 256){
    float v = p[idx];
    s += v; ss += v * v;
  }
  __shared__ float r1[256], r2[256];
  r1[t] = s; r2[t] = ss;
  __syncthreads();
  for (int o = 128; o > 0; o >>= 1){
    if (t < o){ r1[t] += r1[t + o]; r2[t] += r2[t + o]; }
    __syncthreads();
  }
  if (t == 0){ sums[bc] = r1[0]; sumsq[bc] = r2[0]; }
}

__global__ __launch_bounds__(256) void dyrelu_coef_kernel(
    const float* __restrict__ psum, float inv_hw,
    const float* __restrict__ w1, const float* __restrict__ b1,
    const float* __restrict__ w2, const float* __restrict__ b2,
    float* __restrict__ coef){
  int b = blockIdx.x; int t = threadIdx.x;
  __shared__ float pl[CH], hl[64];
  pl[t] = psum[b * CH + t] * inv_hw;
  __syncthreads();
  if (t < 64){
    float a = b1[t];
    const float* wr = w1 + t * CH;
    for (int c = 0; c < CH; c++) a += wr[c] * pl[c];
    hl[t] = fmaxf(a, 0.0f);
  }
  __syncthreads();
  #pragma unroll
  for (int r = 0; r < 4; r++){
    int o = r * CH + t;
    float a = b2[o];
    const float* wr = w2 + o * 64;
    #pragma unroll
    for (int j = 0; j < 64; j++) a += wr[j] * hl[j];
    float co = hsig(a) - 0.5f;
    float outv;
    if (r == 0) outv = co * 2.0f + 1.0f;
    else if (r == 2) outv = co * 2.0f;
    else outv = co;
    coef[(b * 4 + r) * CH + t] = outv;
  }
}

__global__ __launch_bounds__(256) void final_kernel(
    const float* __restrict__ s, const float* __restrict__ coef, float* __restrict__ outp, int HW){
  int idx = blockIdx.x * 256 + threadIdx.x;
  int b = idx / (CH * HW);
  int c = (idx - b * CH * HW) / HW;
  const float* cf = coef + b * 4 * CH;
  float a1 = cf[c], c1 = cf[CH + c], a2 = cf[2 * CH + c], c2 = cf[3 * CH + c];
  float xv = s[idx];
  outp[idx] = fmaxf(xv * a1 + c1, xv * a2 + c2);
}

extern "C" void kernel_launch(void* const* d_in, const int* in_sizes, int n_in,
                              void* d_out, int out_size, void* d_ws, size_t ws_size,
                              hipStream_t stream){
  const float* x0 = (const float*)d_in[0];
  const float* x1 = (const float*)d_in[1];
  const float* x2 = (const float*)d_in[2];
  const float* w_off = (const float*)d_in[3];
  const float* b_off = (const float*)d_in[4];
  int sig = (in_sizes[6] == 256);
  const float* w_high = (const float*)d_in[5];
  const float* w_mid  = (const float*)d_in[sig ? 8 : 6];
  const float* w_low  = (const float*)d_in[sig ? 11 : 7];
  const float* gn_high_w = (const float*)d_in[sig ? 6 : 8];
  const float* gn_high_b = (const float*)d_in[sig ? 7 : 9];
  const float* gn_mid_w  = (const float*)d_in[sig ? 9 : 10];
  const float* gn_mid_b  = (const float*)d_in[sig ? 10 : 11];
  const float* gn_low_w  = (const float*)d_in[12];
  const float* gn_low_b  = (const float*)d_in[13];
  const float* sa_w  = (const float*)d_in[14];
  const float* sa_b  = (const float*)d_in[15];
  const float* dy_w1 = (const float*)d_in[16];
  const float* dy_b1 = (const float*)d_in[17];
  const float* dy_w2 = (const float*)d_in[18];
  const float* dy_b2 = (const float*)d_in[19];

  float* p = (float*)d_ws;
  unsigned short* W3_mid  = (unsigned short*)p; p += 294912;
  unsigned short* W3_low  = (unsigned short*)p; p += 294912;
  unsigned short* W3_high = (unsigned short*)p; p += 294912;
  unsigned short* W27     = (unsigned short*)p; p += 36864;
  float* xn0 = p; p += 4194304;
  float* xn1 = p; p += 1048576;
  float* xn2 = p; p += 262144;
  float* offs_all = p; p += 387072;
  float* mask_all = p; p += 193536;
  float* y_all = p; p += 8126464;
  float* sums_all = p; p += 7168;
  float* ss_all = p; p += 7168;
  float* wsum_all = p; p += 2048;
  float* psum = p; p += 3072;
  float* mu_all = p; p += 448;
  float* rs_all = p; p += 448;
  float* v_all = p; p += 28;   p += 4;  // align
  float* roww0 = p; p += 32;
  float* roww1 = p; p += 32;
  float* coefb = p; p += 4096;

  pack_w_kernel<<<2304, 256, 0, stream>>>(w_mid,  W3_mid);
  pack_w_kernel<<<2304, 256, 0, stream>>>(w_low,  W3_low);
  pack_w_kernel<<<2304, 256, 0, stream>>>(w_high, W3_high);
  pack_woff_kernel<<<288, 256, 0, stream>>>(w_off, W27);
  nhwc_kernel<<<672, 256, 0, stream>>>(x0, x1, x2, xn0, xn1, xn2);
  rowsum2_kernel<<<2, 64, 0, stream>>>(roww0, roww1);

  conv_offset_mfma_kernel<<<336, 256, 0, stream>>>(xn0, xn1, xn2, W27, b_off, offs_all, mask_all);
  mdcn_mfma_kernel<<<496, 256, 0, stream>>>(xn0, xn1, xn2, offs_all, mask_all, W3_mid, W3_low, W3_high, y_all);
  stats_all_kernel<<<7168, 256, 0, stream>>>(y_all, roww0, roww1, sums_all, ss_all, wsum_all);
  gn_sa_all_kernel<<<28, 256, 0, stream>>>(sums_all, ss_all, wsum_all,
                                           gn_mid_w, gn_mid_b, gn_low_w, gn_low_b, gn_high_w, gn_high_b,
                                           sa_w, sa_b, mu_all, rs_all, v_all);

  // per-level epilogue
  const long Ybase[3] = {0, 5242880, 7602176};
  const long Ylo[3]   = {0, 6291456, 7864320};
  const long Yhi[3]   = {4194304, 7340032, 0};
  const int mslot[3] = {0, 2, 5};
  const int lslot[3] = {0, 3, 6};
  const int hslot[3] = {1, 4, 0};
  long out_off = 0;
  for (int lvl = 0; lvl < 3; lvl++){
    int H = 64 >> lvl, W = H, HW = H * W;
    int has_lo = (lvl > 0) ? 1 : 0;
    int has_hi = (lvl < 2) ? 1 : 0;
    float cnt = 1.0f + has_lo + has_hi;
    int ms = mslot[lvl], ls = lslot[lvl], hs = hslot[lvl];
    combine_kernel<<<BB * CH * HW / 256, 256, 0, stream>>>(
        y_all + Ybase[lvl], y_all + Ylo[lvl], y_all + Yhi[lvl],
        mu_all + ms * 64, rs_all + ms * 64, gn_mid_w, gn_mid_b, v_all + ms * 4,
        mu_all + ls * 64, rs_all + ls * 64, gn_low_w, gn_low_b, v_all + ls * 4,
        mu_all + hs * 64, rs_all + hs * 64, gn_high_w, gn_high_b, v_all + hs * 4,
        H, W, has_lo, has_hi, 1.0f / cnt);
    stats_kernel<<<BB * CH, 256, 0, stream>>>(y_all + Ybase[lvl], psum + lvl * 1024, ss_all, HW);
    dyrelu_coef_kernel<<<BB, 256, 0, stream>>>(psum + lvl * 1024, 1.0f / HW, dy_w1, dy_b1, dy_w2, dy_b2, coefb);
    final_kernel<<<BB * CH * HW / 256, 256, 0, stream>>>(y_all + Ybase[lvl], coefb, (float*)d_out + out_off, HW);
    out_off += (long)BB * CH * HW;
  }
}